// Round 3
// baseline (3688.034 us; speedup 1.0000x reference)
//
#include <hip/hip_runtime.h>

#define S_LEN 2048
#define BATCH 2
#define DM 1024
#define NH 16
#define DK 64
#define M_ROWS (BATCH * S_LEN)  // 4096

typedef __bf16 bf16x8 __attribute__((ext_vector_type(8)));
typedef float f32x4 __attribute__((ext_vector_type(4)));

__device__ __forceinline__ float bf2f(unsigned short u) {
    union { unsigned int i; float f; } v;
    v.i = ((unsigned int)u) << 16;
    return v.f;
}

__device__ __forceinline__ unsigned short f2bf(float f) {
    union { float f; unsigned int i; } v;
    v.f = f;
    unsigned int i = v.i;
    if ((i & 0x7fffffffu) > 0x7f800000u) return 0x7fc0;  // NaN
    unsigned int r = (i + 0x7fffu + ((i >> 16) & 1u)) >> 16;
    return (unsigned short)r;
}

__device__ __forceinline__ uint4 pack8(float4 a, float4 b) {
    uint4 r;
    r.x = (unsigned int)f2bf(a.x) | ((unsigned int)f2bf(a.y) << 16);
    r.y = (unsigned int)f2bf(a.z) | ((unsigned int)f2bf(a.w) << 16);
    r.z = (unsigned int)f2bf(b.x) | ((unsigned int)f2bf(b.y) << 16);
    r.w = (unsigned int)f2bf(b.z) | ((unsigned int)f2bf(b.w) << 16);
    return r;
}

// ---------------------------------------------------------------------------
// GEMM: C[m,n] = sum_k A[m,k] * W[n,k] + bias[n]
// A: [M,K] row-major, fp32 (AF32=true) or bf16 (false). W: [N,K] fp32
// (torch Linear weight layout). Staged to LDS as bf16, MFMA 16x16x32_bf16.
// head_split=1: C written bf16 to [B,H,S,DK]; else C written fp32 [M,N].
// 128x128 tile, BK=32, 4 waves (2x2), each wave 4x4 MFMA tiles.
// ---------------------------------------------------------------------------
#define TM 128
#define TN 128
#define TK 32
#define LDSS 40  // padded LDS row stride (elems); 80B rows keep 16B alignment

template <bool AF32>
__global__ __launch_bounds__(256) void gemm_bt(
    const void* __restrict__ Av,
    const float* __restrict__ W,
    const float* __restrict__ bias,
    void* __restrict__ Cv,
    int K, int N, int head_split)
{
    __shared__ unsigned short sA[TM * LDSS];
    __shared__ unsigned short sB[TN * LDSS];

    const int tid  = threadIdx.x;
    const int lane = tid & 63;
    const int wave = tid >> 6;
    const int wm   = (wave >> 1) * 64;
    const int wn   = (wave & 1) * 64;
    const int quad = lane >> 4;
    const int lr   = lane & 15;

    const int m0 = blockIdx.y * TM;
    const int n0 = blockIdx.x * TN;

    f32x4 acc[4][4];
#pragma unroll
    for (int i = 0; i < 4; i++)
#pragma unroll
        for (int j = 0; j < 4; j++) acc[i][j] = (f32x4){0.f, 0.f, 0.f, 0.f};

    // staging: 512 chunks of 8 elems per tile; thread t owns chunks t, t+256
    const int c0 = tid, c1 = tid + 256;
    const int r0 = c0 >> 2, col0 = (c0 & 3) * 8;
    const int r1 = c1 >> 2, col1 = (c1 & 3) * 8;

    const float*          gAf0 = (const float*)Av          + (long)(m0 + r0) * K + col0;
    const float*          gAf1 = (const float*)Av          + (long)(m0 + r1) * K + col1;
    const unsigned short* gAh0 = (const unsigned short*)Av + (long)(m0 + r0) * K + col0;
    const unsigned short* gAh1 = (const unsigned short*)Av + (long)(m0 + r1) * K + col1;
    const float* gW0 = W + (long)(n0 + r0) * K + col0;
    const float* gW1 = W + (long)(n0 + r1) * K + col1;

    uint4 pa0, pa1;
    if constexpr (AF32) {
        pa0 = pack8(*(const float4*)gAf0, *(const float4*)(gAf0 + 4));
        pa1 = pack8(*(const float4*)gAf1, *(const float4*)(gAf1 + 4));
    } else {
        pa0 = *(const uint4*)gAh0;
        pa1 = *(const uint4*)gAh1;
    }
    uint4 pw0 = pack8(*(const float4*)gW0, *(const float4*)(gW0 + 4));
    uint4 pw1 = pack8(*(const float4*)gW1, *(const float4*)(gW1 + 4));

    for (int k0 = 0; k0 < K; k0 += TK) {
        __syncthreads();
        *(uint4*)&sA[r0 * LDSS + col0] = pa0;
        *(uint4*)&sA[r1 * LDSS + col1] = pa1;
        *(uint4*)&sB[r0 * LDSS + col0] = pw0;
        *(uint4*)&sB[r1 * LDSS + col1] = pw1;
        __syncthreads();

        const int kn = k0 + TK;
        if (kn < K) {
            if constexpr (AF32) {
                pa0 = pack8(*(const float4*)(gAf0 + kn), *(const float4*)(gAf0 + kn + 4));
                pa1 = pack8(*(const float4*)(gAf1 + kn), *(const float4*)(gAf1 + kn + 4));
            } else {
                pa0 = *(const uint4*)(gAh0 + kn);
                pa1 = *(const uint4*)(gAh1 + kn);
            }
            pw0 = pack8(*(const float4*)(gW0 + kn), *(const float4*)(gW0 + kn + 4));
            pw1 = pack8(*(const float4*)(gW1 + kn), *(const float4*)(gW1 + kn + 4));
        }

        bf16x8 aF[4], bF[4];
#pragma unroll
        for (int i = 0; i < 4; i++)
            aF[i] = *(const bf16x8*)&sA[(wm + i * 16 + lr) * LDSS + quad * 8];
#pragma unroll
        for (int j = 0; j < 4; j++)
            bF[j] = *(const bf16x8*)&sB[(wn + j * 16 + lr) * LDSS + quad * 8];
#pragma unroll
        for (int i = 0; i < 4; i++)
#pragma unroll
            for (int j = 0; j < 4; j++)
                acc[i][j] = __builtin_amdgcn_mfma_f32_16x16x32_bf16(
                    aF[i], bF[j], acc[i][j], 0, 0, 0);
    }

    // epilogue: C/D layout col=lane&15, row=quad*4+reg
#pragma unroll
    for (int j = 0; j < 4; j++) {
        const int gn = n0 + wn + j * 16 + lr;
        const float bvv = bias[gn];
#pragma unroll
        for (int i = 0; i < 4; i++) {
            const int gmb = m0 + wm + i * 16 + quad * 4;
#pragma unroll
            for (int r = 0; r < 4; r++) {
                const int gm = gmb + r;
                const float val = acc[i][j][r] + bvv;
                if (head_split) {
                    // [b,h,s,d]: b=gm>>11, s=gm&2047, h=gn>>6, d=gn&63
                    const long idx = (long)(gm >> 11) * (NH * S_LEN * DK)
                                   + (long)(gn >> 6) * (S_LEN * DK)
                                   + (long)(gm & (S_LEN - 1)) * DK + (gn & (DK - 1));
                    ((unsigned short*)Cv)[idx] = f2bf(val);
                } else {
                    ((float*)Cv)[(long)gm * N + gn] = val;
                }
            }
        }
    }
}

// ---------------------------------------------------------------------------
// Attention: one block per (b*H+h, q). Scores in LDS fp32, softmax, PV.
// Q/K/V in [B*H, S, DK] bf16. Out written bf16 [B*S, DM] (head-concat).
// ---------------------------------------------------------------------------
__device__ __forceinline__ float dot8(uint4 u, const float* qf) {
    return bf2f((unsigned short)(u.x & 0xffffu)) * qf[0] +
           bf2f((unsigned short)(u.x >> 16)) * qf[1] +
           bf2f((unsigned short)(u.y & 0xffffu)) * qf[2] +
           bf2f((unsigned short)(u.y >> 16)) * qf[3] +
           bf2f((unsigned short)(u.z & 0xffffu)) * qf[4] +
           bf2f((unsigned short)(u.z >> 16)) * qf[5] +
           bf2f((unsigned short)(u.w & 0xffffu)) * qf[6] +
           bf2f((unsigned short)(u.w >> 16)) * qf[7];
}

__global__ __launch_bounds__(256) void attn(
    const unsigned short* __restrict__ Q,
    const unsigned short* __restrict__ Kv,
    const unsigned short* __restrict__ V,
    unsigned short* __restrict__ Out)
{
    __shared__ float sQ[DK];
    __shared__ float sP[S_LEN];
    __shared__ float sRed[8];
    __shared__ float sOut[8 * DK];

    const int q    = blockIdx.x;
    const int bh   = blockIdx.y;  // b*NH + h
    const int t    = threadIdx.x;
    const int lane = t & 63;
    const int wave = t >> 6;

    const long base = (long)bh * S_LEN * DK;

    if (t < DK / 2) {
        unsigned int u = *(const unsigned int*)(Q + base + (long)q * DK + t * 2);
        sQ[t * 2]     = bf2f((unsigned short)(u & 0xffffu));
        sQ[t * 2 + 1] = bf2f((unsigned short)(u >> 16));
    }
    __syncthreads();

    // pass 1: scores (8 keys per thread)
    float lmax = -1e30f;
#pragma unroll
    for (int i = 0; i < 8; i++) {
        const int k = i * 256 + t;
        const uint4* kr = (const uint4*)(Kv + base + (long)k * DK);
        float s = 0.f;
#pragma unroll
        for (int c = 0; c < 8; c++) s += dot8(kr[c], &sQ[c * 8]);
        s *= 0.125f;  // 1/sqrt(64)
        sP[k] = s;
        lmax = fmaxf(lmax, s);
    }
#pragma unroll
    for (int o = 32; o > 0; o >>= 1) lmax = fmaxf(lmax, __shfl_xor(lmax, o, 64));
    if (lane == 0) sRed[wave] = lmax;
    __syncthreads();
    if (t == 0)
        sRed[4] = fmaxf(fmaxf(sRed[0], sRed[1]), fmaxf(sRed[2], sRed[3]));
    __syncthreads();
    const float gmax = sRed[4];

    // pass 2: exp + sum
    float lsum = 0.f;
#pragma unroll
    for (int i = 0; i < 8; i++) {
        const int k = i * 256 + t;
        const float e = __expf(sP[k] - gmax);
        sP[k] = e;
        lsum += e;
    }
#pragma unroll
    for (int o = 32; o > 0; o >>= 1) lsum += __shfl_xor(lsum, o, 64);
    if (lane == 0) sRed[wave] = lsum;
    __syncthreads();
    if (t == 0) sRed[5] = sRed[0] + sRed[1] + sRed[2] + sRed[3];
    __syncthreads();
    const float inv = 1.0f / sRed[5];

    // pass 3: PV. seg = t>>5 handles 256 keys; each thread owns a dim pair.
    const int seg = t >> 5;
    const int dp  = (t & 31) * 2;
    float a0 = 0.f, a1 = 0.f;
    const unsigned short* vb = V + base;
    const int kend = seg * 256 + 256;
#pragma unroll 4
    for (int k = seg * 256; k < kend; k++) {
        const unsigned int u = *(const unsigned int*)(vb + (long)k * DK + dp);
        const float p = sP[k];
        a0 += p * bf2f((unsigned short)(u & 0xffffu));
        a1 += p * bf2f((unsigned short)(u >> 16));
    }
    sOut[seg * DK + dp]     = a0;
    sOut[seg * DK + dp + 1] = a1;
    __syncthreads();

    if (t < DK) {
        float o = 0.f;
#pragma unroll
        for (int sgi = 0; sgi < 8; sgi++) o += sOut[sgi * DK + t];
        o *= inv;
        const int b = bh >> 4, h = bh & (NH - 1);
        const long oi = ((long)(b * S_LEN + q)) * DM + h * DK + t;
        Out[oi] = f2bf(o);
    }
}

// ---------------------------------------------------------------------------
// Residual + LayerNorm (fp32): out = LN(X + O) * gamma + beta, row = 1024
// ---------------------------------------------------------------------------
__global__ __launch_bounds__(256) void ln_res(
    const float* __restrict__ X,
    const float* __restrict__ O,
    const float* __restrict__ gamma,
    const float* __restrict__ beta,
    float* __restrict__ Out)
{
    __shared__ float sR[8];
    const int row = blockIdx.x;
    const int t = threadIdx.x;
    const int lane = t & 63, wave = t >> 6;
    const long off = (long)row * DM + t * 4;

    const float4 x4 = *(const float4*)(X + off);
    const float4 o4 = *(const float4*)(O + off);
    float x[4] = { x4.x + o4.x, x4.y + o4.y, x4.z + o4.z, x4.w + o4.w };

    float s  = x[0] + x[1] + x[2] + x[3];
    float ss = x[0] * x[0] + x[1] * x[1] + x[2] * x[2] + x[3] * x[3];
#pragma unroll
    for (int o2 = 32; o2 > 0; o2 >>= 1) {
        s  += __shfl_xor(s, o2, 64);
        ss += __shfl_xor(ss, o2, 64);
    }
    if (lane == 0) { sR[wave] = s; sR[4 + wave] = ss; }
    __syncthreads();
    if (t == 0) {
        sR[0] = sR[0] + sR[1] + sR[2] + sR[3];
        sR[4] = sR[4] + sR[5] + sR[6] + sR[7];
    }
    __syncthreads();
    const float mean = sR[0] * (1.0f / DM);
    const float var  = sR[4] * (1.0f / DM) - mean * mean;
    const float rstd = rsqrtf(var + 1e-5f);

    const float4 g4 = *(const float4*)(gamma + t * 4);
    const float4 b4 = *(const float4*)(beta + t * 4);
    float4 r;
    r.x = (x[0] - mean) * rstd * g4.x + b4.x;
    r.y = (x[1] - mean) * rstd * g4.y + b4.y;
    r.z = (x[2] - mean) * rstd * g4.z + b4.z;
    r.w = (x[3] - mean) * rstd * g4.w + b4.w;
    *(float4*)(Out + off) = r;
}

// ---------------------------------------------------------------------------
// ws budget: 24 MB live max.
//   [0,8)   MB: Qb bf16 [B,H,S,DK]   -> dead after attn; reused (with Kb) as
//   [8,16)  MB: Kb bf16 [B,H,S,DK]      Ob fp32 [M,DM] (16 MB)
//   [16,24) MB: Vb bf16 [B,H,S,DK]
// Attention output Ab (bf16, 8 MB) lives inside d_out (fp32, 16 MB) and is
// fully overwritten by ln_res at the end.
// ---------------------------------------------------------------------------
extern "C" void kernel_launch(void* const* d_in, const int* in_sizes, int n_in,
                              void* d_out, int out_size, void* d_ws, size_t ws_size,
                              hipStream_t stream)
{
    (void)in_sizes; (void)n_in; (void)out_size; (void)ws_size;
    const float* queries = (const float*)d_in[0];
    const float* keys    = (const float*)d_in[1];
    const float* values  = (const float*)d_in[2];
    const float* Wq = (const float*)d_in[3];
    const float* bq = (const float*)d_in[4];
    const float* Wk = (const float*)d_in[5];
    const float* bk = (const float*)d_in[6];
    const float* Wv = (const float*)d_in[7];
    const float* bv = (const float*)d_in[8];
    const float* Wo = (const float*)d_in[9];
    const float* bo = (const float*)d_in[10];
    const float* gamma = (const float*)d_in[11];
    const float* beta  = (const float*)d_in[12];

    char* ws = (char*)d_ws;
    const size_t MB8 = (size_t)8 * 1024 * 1024;
    unsigned short* Qb = (unsigned short*)(ws);            // bf16 [B,H,S,DK]
    unsigned short* Kb = (unsigned short*)(ws + MB8);      // bf16 [B,H,S,DK]
    unsigned short* Vb = (unsigned short*)(ws + 2 * MB8);  // bf16 [B,H,S,DK]
    unsigned short* Ab = (unsigned short*)d_out;           // bf16 [M,DM] scratch in d_out
    float*          Ob = (float*)(ws);                     // fp32 [M,DM] over Qb+Kb

    dim3 gg(DM / TN, M_ROWS / TM);
    gemm_bt<true><<<gg, 256, 0, stream>>>(queries, Wq, bq, Qb, DM, DM, 1);
    gemm_bt<true><<<gg, 256, 0, stream>>>(keys,    Wk, bk, Kb, DM, DM, 1);
    gemm_bt<true><<<gg, 256, 0, stream>>>(values,  Wv, bv, Vb, DM, DM, 1);
    attn<<<dim3(S_LEN, BATCH * NH), 256, 0, stream>>>(Qb, Kb, Vb, Ab);
    gemm_bt<false><<<gg, 256, 0, stream>>>(Ab, Wo, bo, Ob, DM, DM, 0);
    ln_res<<<M_ROWS, 256, 0, stream>>>(queries, Ob, gamma, beta, (float*)d_out);
}

// Round 4
// 465.879 us; speedup vs baseline: 7.9163x; 7.9163x over previous
//
#include <hip/hip_runtime.h>

#define S_LEN 2048
#define BATCH 2
#define DM 1024
#define NH 16
#define DK 64
#define M_ROWS (BATCH * S_LEN)  // 4096

typedef __bf16 bf16x8 __attribute__((ext_vector_type(8)));
typedef float f32x4 __attribute__((ext_vector_type(4)));

__device__ __forceinline__ float bf2f(unsigned short u) {
    union { unsigned int i; float f; } v;
    v.i = ((unsigned int)u) << 16;
    return v.f;
}

__device__ __forceinline__ unsigned short f2bf(float f) {
    union { float f; unsigned int i; } v;
    v.f = f;
    unsigned int i = v.i;
    if ((i & 0x7fffffffu) > 0x7f800000u) return 0x7fc0;  // NaN
    unsigned int r = (i + 0x7fffu + ((i >> 16) & 1u)) >> 16;
    return (unsigned short)r;
}

__device__ __forceinline__ uint4 pack8(float4 a, float4 b) {
    uint4 r;
    r.x = (unsigned int)f2bf(a.x) | ((unsigned int)f2bf(a.y) << 16);
    r.y = (unsigned int)f2bf(a.z) | ((unsigned int)f2bf(a.w) << 16);
    r.z = (unsigned int)f2bf(b.x) | ((unsigned int)f2bf(b.y) << 16);
    r.w = (unsigned int)f2bf(b.z) | ((unsigned int)f2bf(b.w) << 16);
    return r;
}

// ---------------------------------------------------------------------------
// GEMM: C[m,n] = sum_k A[m,k] * W[n,k] + bias[n]
// A fp32 (AF32) or bf16. W fp32 [N,K] (torch Linear). MFMA 16x16x32_bf16.
// mode 0: C fp32 [M,N]
// mode 1: C bf16 [B,H,S,DK]   (Q/K head-split)
// mode 2: C bf16 [B,H,DK,S]   (V transposed, for flash-attn B-fragments)
// ---------------------------------------------------------------------------
#define TM 128
#define TN 128
#define TK 32
#define LDSS 40  // padded LDS row stride (elems); 80B rows keep 16B alignment

template <bool AF32>
__global__ __launch_bounds__(256) void gemm_bt(
    const void* __restrict__ Av,
    const float* __restrict__ W,
    const float* __restrict__ bias,
    void* __restrict__ Cv,
    int K, int N, int mode)
{
    __shared__ unsigned short sA[TM * LDSS];
    __shared__ unsigned short sB[TN * LDSS];

    const int tid  = threadIdx.x;
    const int lane = tid & 63;
    const int wave = tid >> 6;
    const int wm   = (wave >> 1) * 64;
    const int wn   = (wave & 1) * 64;
    const int quad = lane >> 4;
    const int lr   = lane & 15;

    const int m0 = blockIdx.y * TM;
    const int n0 = blockIdx.x * TN;

    f32x4 acc[4][4];
#pragma unroll
    for (int i = 0; i < 4; i++)
#pragma unroll
        for (int j = 0; j < 4; j++) acc[i][j] = (f32x4){0.f, 0.f, 0.f, 0.f};

    const int c0 = tid, c1 = tid + 256;
    const int r0 = c0 >> 2, col0 = (c0 & 3) * 8;
    const int r1 = c1 >> 2, col1 = (c1 & 3) * 8;

    const float*          gAf0 = (const float*)Av          + (long)(m0 + r0) * K + col0;
    const float*          gAf1 = (const float*)Av          + (long)(m0 + r1) * K + col1;
    const unsigned short* gAh0 = (const unsigned short*)Av + (long)(m0 + r0) * K + col0;
    const unsigned short* gAh1 = (const unsigned short*)Av + (long)(m0 + r1) * K + col1;
    const float* gW0 = W + (long)(n0 + r0) * K + col0;
    const float* gW1 = W + (long)(n0 + r1) * K + col1;

    uint4 pa0, pa1;
    if constexpr (AF32) {
        pa0 = pack8(*(const float4*)gAf0, *(const float4*)(gAf0 + 4));
        pa1 = pack8(*(const float4*)gAf1, *(const float4*)(gAf1 + 4));
    } else {
        pa0 = *(const uint4*)gAh0;
        pa1 = *(const uint4*)gAh1;
    }
    uint4 pw0 = pack8(*(const float4*)gW0, *(const float4*)(gW0 + 4));
    uint4 pw1 = pack8(*(const float4*)gW1, *(const float4*)(gW1 + 4));

    for (int k0 = 0; k0 < K; k0 += TK) {
        __syncthreads();
        *(uint4*)&sA[r0 * LDSS + col0] = pa0;
        *(uint4*)&sA[r1 * LDSS + col1] = pa1;
        *(uint4*)&sB[r0 * LDSS + col0] = pw0;
        *(uint4*)&sB[r1 * LDSS + col1] = pw1;
        __syncthreads();

        const int kn = k0 + TK;
        if (kn < K) {
            if constexpr (AF32) {
                pa0 = pack8(*(const float4*)(gAf0 + kn), *(const float4*)(gAf0 + kn + 4));
                pa1 = pack8(*(const float4*)(gAf1 + kn), *(const float4*)(gAf1 + kn + 4));
            } else {
                pa0 = *(const uint4*)(gAh0 + kn);
                pa1 = *(const uint4*)(gAh1 + kn);
            }
            pw0 = pack8(*(const float4*)(gW0 + kn), *(const float4*)(gW0 + kn + 4));
            pw1 = pack8(*(const float4*)(gW1 + kn), *(const float4*)(gW1 + kn + 4));
        }

        bf16x8 aF[4], bF[4];
#pragma unroll
        for (int i = 0; i < 4; i++)
            aF[i] = *(const bf16x8*)&sA[(wm + i * 16 + lr) * LDSS + quad * 8];
#pragma unroll
        for (int j = 0; j < 4; j++)
            bF[j] = *(const bf16x8*)&sB[(wn + j * 16 + lr) * LDSS + quad * 8];
#pragma unroll
        for (int i = 0; i < 4; i++)
#pragma unroll
            for (int j = 0; j < 4; j++)
                acc[i][j] = __builtin_amdgcn_mfma_f32_16x16x32_bf16(
                    aF[i], bF[j], acc[i][j], 0, 0, 0);
    }

    // epilogue: C/D layout col=lane&15, row=quad*4+reg
#pragma unroll
    for (int j = 0; j < 4; j++) {
        const int gn = n0 + wn + j * 16 + lr;
        const float bvv = bias[gn];
#pragma unroll
        for (int i = 0; i < 4; i++) {
            const int gmb = m0 + wm + i * 16 + quad * 4;
#pragma unroll
            for (int r = 0; r < 4; r++) {
                const int gm = gmb + r;
                const float val = acc[i][j][r] + bvv;
                if (mode == 1) {
                    // [b,h,s,d]
                    const long idx = (long)(gm >> 11) * (NH * S_LEN * DK)
                                   + (long)(gn >> 6) * (S_LEN * DK)
                                   + (long)(gm & (S_LEN - 1)) * DK + (gn & (DK - 1));
                    ((unsigned short*)Cv)[idx] = f2bf(val);
                } else if (mode == 2) {
                    // [b,h,d,s]
                    const long idx = ((long)(gm >> 11) * NH + (gn >> 6)) * (DK * S_LEN)
                                   + (long)(gn & (DK - 1)) * S_LEN + (gm & (S_LEN - 1));
                    ((unsigned short*)Cv)[idx] = f2bf(val);
                } else {
                    ((float*)Cv)[(long)gm * N + gn] = val;
                }
            }
        }
    }
}

// ---------------------------------------------------------------------------
// Flash attention, MFMA. Block = 64 q-rows of one (b,h); 4 waves, 16 q each.
// K-loop: 16 iters x 128 keys. Computes S^T = K·Q^T so the C/D fragment has
// col=q, row=key: lane's 4 acc values = 4 consecutive keys -> ds_write_b64
// into sP[q][key]; PV then reads contiguous A-frags from sP and B-frags
// from V^T ([B,H,DK,S] global layout). Online softmax in exp2 domain.
// LDS: sK 18KB + sVT 17KB + sP 17KB (sP doubles as Q staging) = 52KB.
// ---------------------------------------------------------------------------
__global__ __launch_bounds__(256) void attn_flash(
    const unsigned short* __restrict__ Q,
    const unsigned short* __restrict__ K,
    const unsigned short* __restrict__ Vt,
    unsigned short* __restrict__ Out)
{
    __shared__ unsigned short sK[128 * 72];
    __shared__ unsigned short sVT[64 * 136];
    __shared__ unsigned short sP[64 * 136];

    const int t    = threadIdx.x;
    const int lane = t & 63;
    const int wave = t >> 6;
    const int quad = lane >> 4;
    const int lr   = lane & 15;
    const int q0   = blockIdx.x * 64;
    const int bh   = blockIdx.y;

    const long baseQK = (long)bh * S_LEN * DK;
    const long baseV  = (long)bh * DK * S_LEN;

    // stage Q tile [64][64] into sP (stride 72), preload B-fragments
    {
        const int ca = t, cb = t + 256;
        const uint4 v0 = *(const uint4*)(Q + baseQK + (long)(q0 + (ca >> 3)) * DK + (ca & 7) * 8);
        const uint4 v1 = *(const uint4*)(Q + baseQK + (long)(q0 + (cb >> 3)) * DK + (cb & 7) * 8);
        *(uint4*)&sP[(ca >> 3) * 72 + (ca & 7) * 8] = v0;
        *(uint4*)&sP[(cb >> 3) * 72 + (cb & 7) * 8] = v1;
    }
    __syncthreads();
    bf16x8 qf[2];
    qf[0] = *(const bf16x8*)&sP[(wave * 16 + lr) * 72 + 0 * 32 + quad * 8];
    qf[1] = *(const bf16x8*)&sP[(wave * 16 + lr) * 72 + 1 * 32 + quad * 8];

    f32x4 oacc[4];
#pragma unroll
    for (int nj = 0; nj < 4; nj++) oacc[nj] = (f32x4){0.f, 0.f, 0.f, 0.f};
    float m_run = -1e30f, l_run = 0.f;
    const float cs = 0.18033688011112042f;  // log2(e) / sqrt(64)

    for (int kb = 0; kb < S_LEN / 128; kb++) {
        __syncthreads();
        // stage K tile [128][64] (stride 72) and V^T tile [64][128] (stride 136)
#pragma unroll
        for (int i = 0; i < 4; i++) {
            const int c = t + i * 256;
            const uint4 kv = *(const uint4*)(K + baseQK + (long)(kb * 128 + (c >> 3)) * DK + (c & 7) * 8);
            *(uint4*)&sK[(c >> 3) * 72 + (c & 7) * 8] = kv;
        }
#pragma unroll
        for (int i = 0; i < 4; i++) {
            const int c = t + i * 256;
            const uint4 vv = *(const uint4*)(Vt + baseV + (long)(c >> 4) * S_LEN + kb * 128 + (c & 15) * 8);
            *(uint4*)&sVT[(c >> 4) * 136 + (c & 15) * 8] = vv;
        }
        __syncthreads();

        // S^T = K · Q^T : 8 m-tiles (keys) x 1 n-tile (wave's 16 q) x 2 k-steps
        f32x4 sacc[8];
#pragma unroll
        for (int mi = 0; mi < 8; mi++) {
            sacc[mi] = (f32x4){0.f, 0.f, 0.f, 0.f};
            const bf16x8 a0 = *(const bf16x8*)&sK[(mi * 16 + lr) * 72 + 0 * 32 + quad * 8];
            const bf16x8 a1 = *(const bf16x8*)&sK[(mi * 16 + lr) * 72 + 1 * 32 + quad * 8];
            sacc[mi] = __builtin_amdgcn_mfma_f32_16x16x32_bf16(a0, qf[0], sacc[mi], 0, 0, 0);
            sacc[mi] = __builtin_amdgcn_mfma_f32_16x16x32_bf16(a1, qf[1], sacc[mi], 0, 0, 0);
        }

        // online softmax (exp2 domain), stats per column q = lane&15
        float mloc = -1e30f;
#pragma unroll
        for (int mi = 0; mi < 8; mi++)
#pragma unroll
            for (int r = 0; r < 4; r++) {
                const float tv = sacc[mi][r] * cs;
                sacc[mi][r] = tv;
                mloc = fmaxf(mloc, tv);
            }
        mloc = fmaxf(mloc, __shfl_xor(mloc, 16, 64));
        mloc = fmaxf(mloc, __shfl_xor(mloc, 32, 64));
        const float m_new = fmaxf(m_run, mloc);
        const float alpha = __builtin_amdgcn_exp2f(m_run - m_new);
        m_run = m_new;

        float psum = 0.f;
#pragma unroll
        for (int mi = 0; mi < 8; mi++)
#pragma unroll
            for (int r = 0; r < 4; r++) {
                const float p = __builtin_amdgcn_exp2f(sacc[mi][r] - m_new);
                sacc[mi][r] = p;
                psum += p;
            }
        psum += __shfl_xor(psum, 16, 64);
        psum += __shfl_xor(psum, 32, 64);
        l_run = l_run * alpha + psum;

        float ar[4];
#pragma unroll
        for (int r = 0; r < 4; r++) ar[r] = __shfl(alpha, quad * 4 + r, 64);
#pragma unroll
        for (int nj = 0; nj < 4; nj++)
#pragma unroll
            for (int r = 0; r < 4; r++) oacc[nj][r] *= ar[r];

        // pack P (bf16) into sP[q][key]: 4 consecutive keys per write
#pragma unroll
        for (int mi = 0; mi < 8; mi++) {
            uint2 w;
            w.x = (unsigned int)f2bf(sacc[mi][0]) | ((unsigned int)f2bf(sacc[mi][1]) << 16);
            w.y = (unsigned int)f2bf(sacc[mi][2]) | ((unsigned int)f2bf(sacc[mi][3]) << 16);
            *(uint2*)&sP[(wave * 16 + lr) * 136 + mi * 16 + quad * 4] = w;
        }
        // PV: wave reads only its own sP rows (no barrier needed; same-wave
        // ds ordering via lgkmcnt). O[q][dk] += P[q][key] · Vt[dk][key]
#pragma unroll
        for (int kk = 0; kk < 4; kk++) {
            const bf16x8 pa = *(const bf16x8*)&sP[(wave * 16 + lr) * 136 + kk * 32 + quad * 8];
#pragma unroll
            for (int nj = 0; nj < 4; nj++) {
                const bf16x8 bv = *(const bf16x8*)&sVT[(nj * 16 + lr) * 136 + kk * 32 + quad * 8];
                oacc[nj] = __builtin_amdgcn_mfma_f32_16x16x32_bf16(pa, bv, oacc[nj], 0, 0, 0);
            }
        }
    }

    // epilogue: O /= l, write bf16 [B*S, DM] head-concat
    const float inv = 1.0f / l_run;
    float ivr[4];
#pragma unroll
    for (int r = 0; r < 4; r++) ivr[r] = __shfl(inv, quad * 4 + r, 64);
    const int b = bh >> 4, h = bh & (NH - 1);
#pragma unroll
    for (int nj = 0; nj < 4; nj++)
#pragma unroll
        for (int r = 0; r < 4; r++) {
            const int qg = q0 + wave * 16 + quad * 4 + r;
            const long oi = ((long)(b * S_LEN + qg)) * DM + h * DK + nj * 16 + lr;
            Out[oi] = f2bf(oacc[nj][r] * ivr[r]);
        }
}

// ---------------------------------------------------------------------------
// Residual + LayerNorm (fp32): out = LN(X + O) * gamma + beta, row = 1024
// ---------------------------------------------------------------------------
__global__ __launch_bounds__(256) void ln_res(
    const float* __restrict__ X,
    const float* __restrict__ O,
    const float* __restrict__ gamma,
    const float* __restrict__ beta,
    float* __restrict__ Out)
{
    __shared__ float sR[8];
    const int row = blockIdx.x;
    const int t = threadIdx.x;
    const int lane = t & 63, wave = t >> 6;
    const long off = (long)row * DM + t * 4;

    const float4 x4 = *(const float4*)(X + off);
    const float4 o4 = *(const float4*)(O + off);
    float x[4] = { x4.x + o4.x, x4.y + o4.y, x4.z + o4.z, x4.w + o4.w };

    float s  = x[0] + x[1] + x[2] + x[3];
    float ss = x[0] * x[0] + x[1] * x[1] + x[2] * x[2] + x[3] * x[3];
#pragma unroll
    for (int o2 = 32; o2 > 0; o2 >>= 1) {
        s  += __shfl_xor(s, o2, 64);
        ss += __shfl_xor(ss, o2, 64);
    }
    if (lane == 0) { sR[wave] = s; sR[4 + wave] = ss; }
    __syncthreads();
    if (t == 0) {
        sR[0] = sR[0] + sR[1] + sR[2] + sR[3];
        sR[4] = sR[4] + sR[5] + sR[6] + sR[7];
    }
    __syncthreads();
    const float mean = sR[0] * (1.0f / DM);
    const float var  = sR[4] * (1.0f / DM) - mean * mean;
    const float rstd = rsqrtf(var + 1e-5f);

    const float4 g4 = *(const float4*)(gamma + t * 4);
    const float4 b4 = *(const float4*)(beta + t * 4);
    float4 r;
    r.x = (x[0] - mean) * rstd * g4.x + b4.x;
    r.y = (x[1] - mean) * rstd * g4.y + b4.y;
    r.z = (x[2] - mean) * rstd * g4.z + b4.z;
    r.w = (x[3] - mean) * rstd * g4.w + b4.w;
    *(float4*)(Out + off) = r;
}

// ---------------------------------------------------------------------------
// ws: [0,8) Qb bf16 [B,H,S,DK] | [8,16) Kb | [16,24) Vtb bf16 [B,H,DK,S]
// Ob fp32 [M,DM] (16MB) reuses [0,16) after attn. Attn out (bf16 8MB) lives
// in d_out (fp32 16MB), fully overwritten by ln_res.
// ---------------------------------------------------------------------------
extern "C" void kernel_launch(void* const* d_in, const int* in_sizes, int n_in,
                              void* d_out, int out_size, void* d_ws, size_t ws_size,
                              hipStream_t stream)
{
    (void)in_sizes; (void)n_in; (void)out_size; (void)ws_size;
    const float* queries = (const float*)d_in[0];
    const float* keys    = (const float*)d_in[1];
    const float* values  = (const float*)d_in[2];
    const float* Wq = (const float*)d_in[3];
    const float* bq = (const float*)d_in[4];
    const float* Wk = (const float*)d_in[5];
    const float* bk = (const float*)d_in[6];
    const float* Wv = (const float*)d_in[7];
    const float* bv = (const float*)d_in[8];
    const float* Wo = (const float*)d_in[9];
    const float* bo = (const float*)d_in[10];
    const float* gamma = (const float*)d_in[11];
    const float* beta  = (const float*)d_in[12];

    char* ws = (char*)d_ws;
    const size_t MB8 = (size_t)8 * 1024 * 1024;
    unsigned short* Qb  = (unsigned short*)(ws);            // bf16 [B,H,S,DK]
    unsigned short* Kb  = (unsigned short*)(ws + MB8);      // bf16 [B,H,S,DK]
    unsigned short* Vtb = (unsigned short*)(ws + 2 * MB8);  // bf16 [B,H,DK,S]
    unsigned short* Ab  = (unsigned short*)d_out;           // bf16 [M,DM] scratch
    float*          Ob  = (float*)(ws);                     // fp32 [M,DM]

    dim3 gg(DM / TN, M_ROWS / TM);
    gemm_bt<true><<<gg, 256, 0, stream>>>(queries, Wq, bq, Qb,  DM, DM, 1);
    gemm_bt<true><<<gg, 256, 0, stream>>>(keys,    Wk, bk, Kb,  DM, DM, 1);
    gemm_bt<true><<<gg, 256, 0, stream>>>(values,  Wv, bv, Vtb, DM, DM, 2);
    attn_flash<<<dim3(S_LEN / 64, BATCH * NH), 256, 0, stream>>>(Qb, Kb, Vtb, Ab);
    gemm_bt<false><<<gg, 256, 0, stream>>>(Ab, Wo, bo, Ob, DM, DM, 0);
    ln_res<<<M_ROWS, 256, 0, stream>>>(queries, Ob, gamma, beta, (float*)d_out);
}

// Round 5
// 389.611 us; speedup vs baseline: 9.4659x; 1.1958x over previous
//
#include <hip/hip_runtime.h>

#define S_LEN 2048
#define BATCH 2
#define DM 1024
#define NH 16
#define DK 64
#define M_ROWS (BATCH * S_LEN)  // 4096

typedef __bf16 bf16x8 __attribute__((ext_vector_type(8)));
typedef float f32x4 __attribute__((ext_vector_type(4)));
typedef unsigned int u32;

__device__ __forceinline__ float bf2f(unsigned short u) {
    union { u32 i; float f; } v;
    v.i = ((u32)u) << 16;
    return v.f;
}

// round-to-nearest-even fp32 -> bf16 (finite inputs only)
__device__ __forceinline__ unsigned short rne16(float f) {
    u32 i = __builtin_bit_cast(u32, f);
    return (unsigned short)((i + 0x7fffu + ((i >> 16) & 1u)) >> 16);
}

// pack two fp32 -> bf16x2 (round-half-up; values finite)
__device__ __forceinline__ u32 pk2(float x, float y) {
    u32 a = __builtin_bit_cast(u32, x) + 0x8000u;
    u32 b = __builtin_bit_cast(u32, y) + 0x8000u;
    return (a >> 16) | (b & 0xffff0000u);
}

// async global->LDS 16B per lane (DMA; lds dest = wave base + lane*16)
__device__ __forceinline__ void async16(const void* g, void* l) {
    __builtin_amdgcn_global_load_lds(
        (const __attribute__((address_space(1))) u32*)((unsigned long long)g),
        (__attribute__((address_space(3))) u32*)((u32)(unsigned long long)l),
        16, 0, 0);
}

// ---------------------------------------------------------------------------
// fp32 -> bf16 conversion (8 elems/thread)
// ---------------------------------------------------------------------------
__global__ __launch_bounds__(256) void cvt_bf16(
    const float* __restrict__ src, unsigned short* __restrict__ dst)
{
    const long i = ((long)blockIdx.x * 256 + threadIdx.x) * 8;
    const float4 a = *(const float4*)(src + i);
    const float4 b = *(const float4*)(src + i + 4);
    uint4 r;
    r.x = pk2(a.x, a.y);
    r.y = pk2(a.z, a.w);
    r.z = pk2(b.x, b.y);
    r.w = pk2(b.z, b.w);
    *(uint4*)(dst + i) = r;
}

// ---------------------------------------------------------------------------
// bf16 GEMM: C[m,n] = (sum_k A[m,k]*W[n,k] + bias[n]) * scale
// A [4096,1024] bf16, W [1024,1024] bf16 (torch Linear layout). K=N=1024.
// 128x128 tile, BK=32, global_load_lds staging, unpadded [128][32] LDS.
// mode 1: bf16 [B,H,S,DK]; mode 2: bf16 [B,H,DK,S]; mode 3: bf16 [M,N].
// ---------------------------------------------------------------------------
__global__ __launch_bounds__(256) void gemm16(
    const unsigned short* __restrict__ A,
    const unsigned short* __restrict__ W,
    const float* __restrict__ bias,
    unsigned short* __restrict__ C,
    float scale, int mode)
{
    __shared__ unsigned short sA[128 * 32];
    __shared__ unsigned short sB[128 * 32];

    const int t    = threadIdx.x;
    const int lane = t & 63;
    const int wave = t >> 6;
    const int wm   = (wave >> 1) * 64;
    const int wn   = (wave & 1) * 64;
    const int quad = lane >> 4;
    const int lr   = lane & 15;
    const int m0   = blockIdx.y * 128;
    const int n0   = blockIdx.x * 128;

    f32x4 acc[4][4];
#pragma unroll
    for (int i = 0; i < 4; i++)
#pragma unroll
        for (int j = 0; j < 4; j++) acc[i][j] = (f32x4){0.f, 0.f, 0.f, 0.f};

    // chunk c (16B) <-> lds elems [c*8, c*8+8) <-> row c>>2, col (c&3)*8
    const unsigned short* ga0 = A + (long)(m0 + (t >> 2)) * 1024 + (t & 3) * 8;
    const unsigned short* ga1 = ga0 + 64 * 1024;
    const unsigned short* gw0 = W + (long)(n0 + (t >> 2)) * 1024 + (t & 3) * 8;
    const unsigned short* gw1 = gw0 + 64 * 1024;

    for (int k0 = 0; k0 < 1024; k0 += 32) {
        __syncthreads();
        async16(ga0 + k0, &sA[t * 8]);
        async16(ga1 + k0, &sA[(t + 256) * 8]);
        async16(gw0 + k0, &sB[t * 8]);
        async16(gw1 + k0, &sB[(t + 256) * 8]);
        __syncthreads();

        bf16x8 aF[4], bF[4];
#pragma unroll
        for (int i = 0; i < 4; i++)
            aF[i] = *(const bf16x8*)&sA[(wm + i * 16 + lr) * 32 + quad * 8];
#pragma unroll
        for (int j = 0; j < 4; j++)
            bF[j] = *(const bf16x8*)&sB[(wn + j * 16 + lr) * 32 + quad * 8];
#pragma unroll
        for (int i = 0; i < 4; i++)
#pragma unroll
            for (int j = 0; j < 4; j++)
                acc[i][j] = __builtin_amdgcn_mfma_f32_16x16x32_bf16(
                    aF[i], bF[j], acc[i][j], 0, 0, 0);
    }

    // epilogue: C/D layout col=lane&15, row=quad*4+reg
#pragma unroll
    for (int j = 0; j < 4; j++) {
        const int gn = n0 + wn + j * 16 + lr;
        const float bvv = bias[gn];
#pragma unroll
        for (int i = 0; i < 4; i++) {
            const int gmb = m0 + wm + i * 16 + quad * 4;
#pragma unroll
            for (int r = 0; r < 4; r++) {
                const int gm = gmb + r;
                const float val = (acc[i][j][r] + bvv) * scale;
                long idx;
                if (mode == 1) {
                    idx = (long)(gm >> 11) * (NH * S_LEN * DK)
                        + (long)(gn >> 6) * (S_LEN * DK)
                        + (long)(gm & (S_LEN - 1)) * DK + (gn & (DK - 1));
                } else if (mode == 2) {
                    idx = ((long)(gm >> 11) * NH + (gn >> 6)) * (DK * S_LEN)
                        + (long)(gn & (DK - 1)) * S_LEN + (gm & (S_LEN - 1));
                } else {
                    idx = (long)gm * 1024 + gn;
                }
                C[idx] = rne16(val);
            }
        }
    }
}

// ---------------------------------------------------------------------------
// Flash attention. Block = 64 q of one (b,h); 4 waves x 16 q.
// Q pre-scaled by log2(e)/sqrt(dk) in projection. K staged by global_load_lds
// into split-half [2][128][32] LDS; V frags loaded directly from global V^T.
// P round-trips via wave-private sP rows. LDS = 16KB + 17KB = 33KB.
// ---------------------------------------------------------------------------
__global__ __launch_bounds__(256) void attn_flash(
    const unsigned short* __restrict__ Q,
    const unsigned short* __restrict__ K,
    const unsigned short* __restrict__ Vt,
    unsigned short* __restrict__ Out)
{
    __shared__ unsigned short sK[2 * 128 * 32];  // [half][128 keys][32]
    __shared__ unsigned short sP[64 * 136];      // P rows (also Q staging @72)

    const int t    = threadIdx.x;
    const int lane = t & 63;
    const int wave = t >> 6;
    const int quad = lane >> 4;
    const int lr   = lane & 15;
    const int q0   = blockIdx.x * 64;
    const int bh   = blockIdx.y;

    const long baseQK = (long)bh * S_LEN * DK;
    const long baseV  = (long)bh * DK * S_LEN;

    // stage Q tile [64][64] into sP (stride 72), load B-frags to regs
    {
        const int ca = t, cb = t + 256;
        const uint4 v0 = *(const uint4*)(Q + baseQK + (long)(q0 + (ca >> 3)) * DK + (ca & 7) * 8);
        const uint4 v1 = *(const uint4*)(Q + baseQK + (long)(q0 + (cb >> 3)) * DK + (cb & 7) * 8);
        *(uint4*)&sP[(ca >> 3) * 72 + (ca & 7) * 8] = v0;
        *(uint4*)&sP[(cb >> 3) * 72 + (cb & 7) * 8] = v1;
    }
    __syncthreads();
    bf16x8 qf[2];
    qf[0] = *(const bf16x8*)&sP[(wave * 16 + lr) * 72 + 0 * 32 + quad * 8];
    qf[1] = *(const bf16x8*)&sP[(wave * 16 + lr) * 72 + 1 * 32 + quad * 8];

    // per-thread K DMA sources: lds chunk l = t + i*256 holds global chunk
    // (row = (l&511)>>2, col = ((l>>9)*4 + (l&3))*8) of the 128x64 K tile
    const unsigned short* gK[4];
#pragma unroll
    for (int i = 0; i < 4; i++) {
        const int l = t + i * 256;
        const int row = (l & 511) >> 2;
        const int colc = (l >> 9) * 4 + (l & 3);
        gK[i] = K + baseQK + row * 64 + colc * 8;
    }

    f32x4 oacc[4];
#pragma unroll
    for (int nj = 0; nj < 4; nj++) oacc[nj] = (f32x4){0.f, 0.f, 0.f, 0.f};
    float m_run = -1e30f, l_run = 0.f;

    for (int kb = 0; kb < S_LEN / 128; kb++) {
        __syncthreads();
#pragma unroll
        for (int i = 0; i < 4; i++)
            async16(gK[i] + (long)kb * 128 * DK, &sK[(t + i * 256) * 8]);
        // V fragments straight from global (drained by the same barrier)
        uint4 bvr[16];
#pragma unroll
        for (int nj = 0; nj < 4; nj++)
#pragma unroll
            for (int kk = 0; kk < 4; kk++)
                bvr[nj * 4 + kk] = *(const uint4*)(Vt + baseV
                    + (long)(nj * 16 + lr) * S_LEN + kb * 128 + kk * 32 + quad * 8);
        __syncthreads();

        // S^T = K · Q^T (q pre-scaled): 8 key-tiles x wave's 16 q
        f32x4 sacc[8];
#pragma unroll
        for (int mi = 0; mi < 8; mi++) {
            sacc[mi] = (f32x4){0.f, 0.f, 0.f, 0.f};
            const bf16x8 a0 = *(const bf16x8*)&sK[0 * 4096 + (mi * 16 + lr) * 32 + quad * 8];
            const bf16x8 a1 = *(const bf16x8*)&sK[1 * 4096 + (mi * 16 + lr) * 32 + quad * 8];
            sacc[mi] = __builtin_amdgcn_mfma_f32_16x16x32_bf16(a0, qf[0], sacc[mi], 0, 0, 0);
            sacc[mi] = __builtin_amdgcn_mfma_f32_16x16x32_bf16(a1, qf[1], sacc[mi], 0, 0, 0);
        }

        // online softmax in exp2 domain; stats per q-column (lane&15)
        float mloc = -1e30f;
#pragma unroll
        for (int mi = 0; mi < 8; mi++)
#pragma unroll
            for (int r = 0; r < 4; r++) mloc = fmaxf(mloc, sacc[mi][r]);
        mloc = fmaxf(mloc, __shfl_xor(mloc, 16, 64));
        mloc = fmaxf(mloc, __shfl_xor(mloc, 32, 64));
        const float m_new = fmaxf(m_run, mloc);
        const float alpha = __builtin_amdgcn_exp2f(m_run - m_new);
        m_run = m_new;

        float psum = 0.f;
#pragma unroll
        for (int mi = 0; mi < 8; mi++)
#pragma unroll
            for (int r = 0; r < 4; r++) {
                const float p = __builtin_amdgcn_exp2f(sacc[mi][r] - m_new);
                sacc[mi][r] = p;
                psum += p;
            }
        psum += __shfl_xor(psum, 16, 64);
        psum += __shfl_xor(psum, 32, 64);
        l_run = l_run * alpha + psum;

        float ar[4];
#pragma unroll
        for (int r = 0; r < 4; r++) ar[r] = __shfl(alpha, quad * 4 + r, 64);
#pragma unroll
        for (int nj = 0; nj < 4; nj++)
#pragma unroll
            for (int r = 0; r < 4; r++) oacc[nj][r] *= ar[r];

        // pack P (bf16) into wave-private sP rows: 4 consecutive keys/write
#pragma unroll
        for (int mi = 0; mi < 8; mi++) {
            uint2 w;
            w.x = pk2(sacc[mi][0], sacc[mi][1]);
            w.y = pk2(sacc[mi][2], sacc[mi][3]);
            *(uint2*)&sP[(wave * 16 + lr) * 136 + mi * 16 + quad * 4] = w;
        }
        // PV: O[q][dk] += P[q][key] · Vt[dk][key]
#pragma unroll
        for (int kk = 0; kk < 4; kk++) {
            const bf16x8 pa = *(const bf16x8*)&sP[(wave * 16 + lr) * 136 + kk * 32 + quad * 8];
#pragma unroll
            for (int nj = 0; nj < 4; nj++) {
                const bf16x8 bb = *(const bf16x8*)&bvr[nj * 4 + kk];
                oacc[nj] = __builtin_amdgcn_mfma_f32_16x16x32_bf16(pa, bb, oacc[nj], 0, 0, 0);
            }
        }
    }

    // epilogue: O /= l, write bf16 [B*S, DM] head-concat
    const float inv = 1.0f / l_run;
    float ivr[4];
#pragma unroll
    for (int r = 0; r < 4; r++) ivr[r] = __shfl(inv, quad * 4 + r, 64);
    const int b = bh >> 4, h = bh & (NH - 1);
#pragma unroll
    for (int nj = 0; nj < 4; nj++)
#pragma unroll
        for (int r = 0; r < 4; r++) {
            const int qg = q0 + wave * 16 + quad * 4 + r;
            const long oi = ((long)(b * S_LEN + qg)) * DM + h * DK + nj * 16 + lr;
            Out[oi] = rne16(oacc[nj][r] * ivr[r]);
        }
}

// ---------------------------------------------------------------------------
// Residual + LayerNorm: out = LN(X + O) * gamma + beta. X fp32, O bf16.
// ---------------------------------------------------------------------------
__global__ __launch_bounds__(256) void ln_res(
    const float* __restrict__ X,
    const unsigned short* __restrict__ O,
    const float* __restrict__ gamma,
    const float* __restrict__ beta,
    float* __restrict__ Out)
{
    __shared__ float sR[8];
    const int row = blockIdx.x;
    const int t = threadIdx.x;
    const int lane = t & 63, wave = t >> 6;
    const long off = (long)row * DM + t * 4;

    const float4 x4 = *(const float4*)(X + off);
    const uint2  uo = *(const uint2*)(O + off);
    float x[4];
    x[0] = x4.x + bf2f((unsigned short)(uo.x & 0xffffu));
    x[1] = x4.y + bf2f((unsigned short)(uo.x >> 16));
    x[2] = x4.z + bf2f((unsigned short)(uo.y & 0xffffu));
    x[3] = x4.w + bf2f((unsigned short)(uo.y >> 16));

    float s  = x[0] + x[1] + x[2] + x[3];
    float ss = x[0] * x[0] + x[1] * x[1] + x[2] * x[2] + x[3] * x[3];
#pragma unroll
    for (int o2 = 32; o2 > 0; o2 >>= 1) {
        s  += __shfl_xor(s, o2, 64);
        ss += __shfl_xor(ss, o2, 64);
    }
    if (lane == 0) { sR[wave] = s; sR[4 + wave] = ss; }
    __syncthreads();
    if (t == 0) {
        sR[0] = sR[0] + sR[1] + sR[2] + sR[3];
        sR[4] = sR[4] + sR[5] + sR[6] + sR[7];
    }
    __syncthreads();
    const float mean = sR[0] * (1.0f / DM);
    const float var  = sR[4] * (1.0f / DM) - mean * mean;
    const float rstd = rsqrtf(var + 1e-5f);

    const float4 g4 = *(const float4*)(gamma + t * 4);
    const float4 b4 = *(const float4*)(beta + t * 4);
    float4 r;
    r.x = (x[0] - mean) * rstd * g4.x + b4.x;
    r.y = (x[1] - mean) * rstd * g4.y + b4.y;
    r.z = (x[2] - mean) * rstd * g4.z + b4.z;
    r.w = (x[3] - mean) * rstd * g4.w + b4.w;
    *(float4*)(Out + off) = r;
}

// ---------------------------------------------------------------------------
// ws (34 MB): [0,8) A16 bf16 input scratch -> later Ob bf16 [M,DM]
//             [8,10) W16 bf16 weight scratch (reused per GEMM)
//             [10,18) Qb [B,H,S,DK] (pre-scaled)  [18,26) Kb  [26,34) Vtb
// Attn out Ab (bf16 8MB) lives in d_out (fp32 16MB), overwritten by ln_res.
// ---------------------------------------------------------------------------
extern "C" void kernel_launch(void* const* d_in, const int* in_sizes, int n_in,
                              void* d_out, int out_size, void* d_ws, size_t ws_size,
                              hipStream_t stream)
{
    (void)in_sizes; (void)n_in; (void)out_size; (void)ws_size;
    const float* queries = (const float*)d_in[0];
    const float* keys    = (const float*)d_in[1];
    const float* values  = (const float*)d_in[2];
    const float* Wq = (const float*)d_in[3];
    const float* bq = (const float*)d_in[4];
    const float* Wk = (const float*)d_in[5];
    const float* bk = (const float*)d_in[6];
    const float* Wv = (const float*)d_in[7];
    const float* bv = (const float*)d_in[8];
    const float* Wo = (const float*)d_in[9];
    const float* bo = (const float*)d_in[10];
    const float* gamma = (const float*)d_in[11];
    const float* beta  = (const float*)d_in[12];

    char* ws = (char*)d_ws;
    const size_t MB = (size_t)1024 * 1024;
    unsigned short* A16 = (unsigned short*)(ws);            // 8 MB
    unsigned short* W16 = (unsigned short*)(ws + 8 * MB);   // 2 MB
    unsigned short* Qb  = (unsigned short*)(ws + 10 * MB);  // 8 MB
    unsigned short* Kb  = (unsigned short*)(ws + 18 * MB);  // 8 MB
    unsigned short* Vtb = (unsigned short*)(ws + 26 * MB);  // 8 MB
    unsigned short* Ab  = (unsigned short*)d_out;           // bf16 scratch
    unsigned short* Ob  = A16;                              // bf16 [M,DM]

    const float CS = 0.18033688011112042f;  // log2(e)/sqrt(64)
    dim3 gg(DM / 128, M_ROWS / 128);

    cvt_bf16<<<2048, 256, 0, stream>>>(queries, A16);
    cvt_bf16<<<512,  256, 0, stream>>>(Wq, W16);
    gemm16<<<gg, 256, 0, stream>>>(A16, W16, bq, Qb, CS, 1);

    cvt_bf16<<<2048, 256, 0, stream>>>(keys, A16);
    cvt_bf16<<<512,  256, 0, stream>>>(Wk, W16);
    gemm16<<<gg, 256, 0, stream>>>(A16, W16, bk, Kb, 1.0f, 1);

    cvt_bf16<<<2048, 256, 0, stream>>>(values, A16);
    cvt_bf16<<<512,  256, 0, stream>>>(Wv, W16);
    gemm16<<<gg, 256, 0, stream>>>(A16, W16, bv, Vtb, 1.0f, 2);

    attn_flash<<<dim3(S_LEN / 64, BATCH * NH), 256, 0, stream>>>(Qb, Kb, Vtb, Ab);

    cvt_bf16<<<512, 256, 0, stream>>>(Wo, W16);
    gemm16<<<gg, 256, 0, stream>>>(Ab, W16, bo, Ob, 1.0f, 3);

    ln_res<<<M_ROWS, 256, 0, stream>>>(queries, Ob, gamma, beta, (float*)d_out);
}

// Round 6
// 277.617 us; speedup vs baseline: 13.2846x; 1.4034x over previous
//
#include <hip/hip_runtime.h>

#define S_LEN 2048
#define BATCH 2
#define DM 1024
#define NH 16
#define DK 64
#define M_ROWS 4096

typedef __bf16 bf16x8 __attribute__((ext_vector_type(8)));
typedef float f32x4 __attribute__((ext_vector_type(4)));
typedef unsigned int u32;
typedef unsigned short u16;

__device__ __forceinline__ float bf2f(u16 u) {
    union { u32 i; float f; } v;
    v.i = ((u32)u) << 16;
    return v.f;
}

// round-to-nearest-even fp32 -> bf16 (finite)
__device__ __forceinline__ u16 rne16(float f) {
    u32 i = __builtin_bit_cast(u32, f);
    return (u16)((i + 0x7fffu + ((i >> 16) & 1u)) >> 16);
}

// pack two fp32 -> bf16x2 (round-half-up; finite)
__device__ __forceinline__ u32 pk2(float x, float y) {
    u32 a = __builtin_bit_cast(u32, x) + 0x8000u;
    u32 b = __builtin_bit_cast(u32, y) + 0x8000u;
    return (a >> 16) | (b & 0xffff0000u);
}

// async global->LDS, 16B per lane
__device__ __forceinline__ void async16(const void* g, void* l) {
    __builtin_amdgcn_global_load_lds(
        (const __attribute__((address_space(1))) u32*)((unsigned long long)g),
        (__attribute__((address_space(3))) u32*)((u32)(unsigned long long)l),
        16, 0, 0);
}

// ---------------------------------------------------------------------------
// One-shot fp32->bf16 of all 7 tensors. Block b covers 2048 elems.
// regions: [0,2048) q | [2048,4096) k | [4096,6144) v | then 512 blocks each
// for Wq, Wk, Wv, Wo.
// ---------------------------------------------------------------------------
__global__ __launch_bounds__(256) void cvt_all(
    const float* __restrict__ q, const float* __restrict__ k,
    const float* __restrict__ v, const float* __restrict__ wq,
    const float* __restrict__ wk, const float* __restrict__ wv,
    const float* __restrict__ wo,
    u16* q16, u16* k16, u16* v16, u16* wq16, u16* wk16, u16* wv16, u16* wo16)
{
    const int b = blockIdx.x;
    const float* src; u16* dst; long off;
    if (b < 2048)      { src = q;  dst = q16;  off = (long)b * 2048; }
    else if (b < 4096) { src = k;  dst = k16;  off = (long)(b - 2048) * 2048; }
    else if (b < 6144) { src = v;  dst = v16;  off = (long)(b - 4096) * 2048; }
    else if (b < 6656) { src = wq; dst = wq16; off = (long)(b - 6144) * 2048; }
    else if (b < 7168) { src = wk; dst = wk16; off = (long)(b - 6656) * 2048; }
    else if (b < 7680) { src = wv; dst = wv16; off = (long)(b - 7168) * 2048; }
    else               { src = wo; dst = wo16; off = (long)(b - 7680) * 2048; }
    const long i = off + (long)threadIdx.x * 8;
    const float4 a = *(const float4*)(src + i);
    const float4 c = *(const float4*)(src + i + 4);
    uint4 r;
    r.x = pk2(a.x, a.y); r.y = pk2(a.z, a.w);
    r.z = pk2(c.x, c.y); r.w = pk2(c.z, c.w);
    *(uint4*)(dst + i) = r;
}

// ---------------------------------------------------------------------------
// bf16 GEMM, 128(M)x64(N) tile, BK=32, K=N=1024. Dual arg-set; blockIdx.z
// selects (for fused Q+K launch). global_load_lds staging with XOR-swizzled
// chunk placement: chunk (row,c) -> pos row*4 + (c ^ (row&3)) -> conflict-
// free a/b-frag ds_read_b128. 4 waves, wave owns 32 m-rows x 64 n.
// mode 1: bf16 [B,H,S,DK]; mode 2: bf16 [B,H,DK,S]; mode 3: bf16 [M,N].
// ---------------------------------------------------------------------------
__global__ __launch_bounds__(256) void gemm64(
    const u16* __restrict__ A0, const u16* __restrict__ W0,
    const float* __restrict__ bias0, u16* __restrict__ C0, float sc0, int md0,
    const u16* __restrict__ A1, const u16* __restrict__ W1,
    const float* __restrict__ bias1, u16* __restrict__ C1, float sc1, int md1)
{
    __shared__ u16 sA[128 * 32];
    __shared__ u16 sB[64 * 32];

    const u16* A = blockIdx.z ? A1 : A0;
    const u16* W = blockIdx.z ? W1 : W0;
    const float* bias = blockIdx.z ? bias1 : bias0;
    u16* C = blockIdx.z ? C1 : C0;
    const float scale = blockIdx.z ? sc1 : sc0;
    const int mode = blockIdx.z ? md1 : md0;

    const int t    = threadIdx.x;
    const int lane = t & 63;
    const int wave = t >> 6;
    const int quad = lane >> 4;
    const int lr   = lane & 15;
    const int wm   = wave * 32;
    const int m0   = blockIdx.y * 128;
    const int n0   = blockIdx.x * 64;

    f32x4 acc[2][4];
#pragma unroll
    for (int i = 0; i < 2; i++)
#pragma unroll
        for (int j = 0; j < 4; j++) acc[i][j] = (f32x4){0.f, 0.f, 0.f, 0.f};

    // DMA sources with swizzled placement
    const int la1 = t + 256;
    const int ra0 = t >> 2,   ca0 = (t & 3)   ^ (ra0 & 3);
    const int ra1 = la1 >> 2, ca1 = (la1 & 3) ^ (ra1 & 3);
    const int rb  = t >> 2,   cb  = (t & 3)   ^ (rb & 3);
    const u16* gA0 = A + (long)(m0 + ra0) * 1024 + ca0 * 8;
    const u16* gA1 = A + (long)(m0 + ra1) * 1024 + ca1 * 8;
    const u16* gW  = W + (long)(n0 + rb) * 1024 + cb * 8;

    const int sw = quad ^ (lr & 3);

    for (int k0 = 0; k0 < 1024; k0 += 32) {
        __syncthreads();
        async16(gA0 + k0, &sA[t * 8]);
        async16(gA1 + k0, &sA[la1 * 8]);
        async16(gW + k0, &sB[t * 8]);
        __syncthreads();

        bf16x8 aF[2], bF[4];
#pragma unroll
        for (int i = 0; i < 2; i++)
            aF[i] = *(const bf16x8*)&sA[((wm + i * 16 + lr) * 4 + sw) * 8];
#pragma unroll
        for (int j = 0; j < 4; j++)
            bF[j] = *(const bf16x8*)&sB[((j * 16 + lr) * 4 + sw) * 8];
#pragma unroll
        for (int i = 0; i < 2; i++)
#pragma unroll
            for (int j = 0; j < 4; j++)
                acc[i][j] = __builtin_amdgcn_mfma_f32_16x16x32_bf16(
                    aF[i], bF[j], acc[i][j], 0, 0, 0);
    }

    // epilogue: C/D layout col=lane&15, row=quad*4+reg
#pragma unroll
    for (int j = 0; j < 4; j++) {
        const int gn = n0 + j * 16 + lr;
        const float bvv = bias[gn];
#pragma unroll
        for (int i = 0; i < 2; i++) {
            const int gmb = m0 + wm + i * 16 + quad * 4;
#pragma unroll
            for (int r = 0; r < 4; r++) {
                const int gm = gmb + r;
                const float val = (acc[i][j][r] + bvv) * scale;
                long idx;
                if (mode == 1) {
                    idx = (long)(gm >> 11) * (NH * S_LEN * DK)
                        + (long)(gn >> 6) * (S_LEN * DK)
                        + (long)(gm & (S_LEN - 1)) * DK + (gn & (DK - 1));
                } else if (mode == 2) {
                    idx = ((long)(gm >> 11) * NH + (gn >> 6)) * (DK * S_LEN)
                        + (long)(gn & (DK - 1)) * S_LEN + (gm & (S_LEN - 1));
                } else {
                    idx = (long)gm * 1024 + gn;
                }
                C[idx] = rne16(val);
            }
        }
    }
}

// ---------------------------------------------------------------------------
// Flash attention. Block = 128 q of one (b,h); 4 waves, each 2 qsets of 16.
// K DMA double-buffered ([2][half][128][32], XOR-swizzled chunk placement);
// one barrier/iter; DMA for kb+1 issued at top of iter kb, drained by the
// compiler's vmcnt(0)-before-barrier one full iter later. V frags loaded from
// global V^T at iter top, consumed ~600cy later in PV. Q pre-scaled by
// log2(e)/sqrt(dk). P round-trips via wave-private sP rows (stride 80).
// LDS: sK 32KB + sP 20KB = 52KB.
// ---------------------------------------------------------------------------
__global__ __launch_bounds__(256, 2) void attn_flash(
    const u16* __restrict__ Q,
    const u16* __restrict__ K,
    const u16* __restrict__ Vt,
    u16* __restrict__ Out)
{
    __shared__ u16 sK[2][8192];   // [buf][half*512 + row*4 + swz-chunk][8]
    __shared__ u16 sP[128 * 80];  // P rows (Q staged here first @ stride 72)

    const int t    = threadIdx.x;
    const int lane = t & 63;
    const int wave = t >> 6;
    const int quad = lane >> 4;
    const int lr   = lane & 15;
    const int q0   = blockIdx.x * 128;
    const int bh   = blockIdx.y;

    const long baseQK = (long)bh * S_LEN * DK;
    const long baseV  = (long)bh * DK * S_LEN;

    // stage Q [128][64] into sP (stride 72)
#pragma unroll
    for (int i = 0; i < 4; i++) {
        const int l = t + i * 256;
        const int row = l >> 3, c8 = l & 7;
        *(uint4*)&sP[row * 72 + c8 * 8] =
            *(const uint4*)(Q + baseQK + (long)(q0 + row) * DK + c8 * 8);
    }

    // K DMA source addresses (swizzled placement)
    const u16* gK[4];
#pragma unroll
    for (int i = 0; i < 4; i++) {
        const int l = t + i * 256;
        const int h = l >> 9, rem = l & 511;
        const int row = rem >> 2, c = (rem & 3) ^ (row & 3);
        gK[i] = K + baseQK + row * DK + h * 32 + c * 8;
    }
    // prologue: DMA K tile 0 into sK[0]
#pragma unroll
    for (int i = 0; i < 4; i++)
        async16(gK[i], &sK[0][(t + i * 256) * 8]);
    __syncthreads();

    bf16x8 qf[2][2];
#pragma unroll
    for (int s = 0; s < 2; s++)
#pragma unroll
        for (int h = 0; h < 2; h++)
            qf[s][h] = *(const bf16x8*)&sP[(s * 64 + wave * 16 + lr) * 72 + h * 32 + quad * 8];

    f32x4 oacc[2][4];
#pragma unroll
    for (int s = 0; s < 2; s++)
#pragma unroll
        for (int nj = 0; nj < 4; nj++) oacc[s][nj] = (f32x4){0.f, 0.f, 0.f, 0.f};
    float m_run[2] = {-1e30f, -1e30f}, l_run[2] = {0.f, 0.f};

    const int sw = quad ^ (lr & 3);

    for (int kb = 0; kb < S_LEN / 128; kb++) {
        const int buf = kb & 1, nb = buf ^ 1;
        __syncthreads();  // prev compute done; sK[buf] DMA visible

        // V fragments for THIS iter (consumed in PV, late in the body)
        uint4 bvr[16];
#pragma unroll
        for (int nj = 0; nj < 4; nj++)
#pragma unroll
            for (int kk = 0; kk < 4; kk++)
                bvr[nj * 4 + kk] = *(const uint4*)(Vt + baseV
                    + (long)(nj * 16 + lr) * S_LEN + kb * 128 + kk * 32 + quad * 8);

        // prefetch K tile kb+1 into the other buffer
        if (kb + 1 < S_LEN / 128) {
#pragma unroll
            for (int i = 0; i < 4; i++)
                async16(gK[i] + (long)(kb + 1) * 128 * DK, &sK[nb][(t + i * 256) * 8]);
        }

        // S^T = K·Q^T (Q pre-scaled): 8 key-tiles x 2 qsets
        f32x4 sacc[8][2];
#pragma unroll
        for (int mi = 0; mi < 8; mi++) {
            const bf16x8 a0 = *(const bf16x8*)&sK[buf][(((mi * 16 + lr) * 4) + sw) * 8];
            const bf16x8 a1 = *(const bf16x8*)&sK[buf][((512 + (mi * 16 + lr) * 4) + sw) * 8];
            const f32x4 z = (f32x4){0.f, 0.f, 0.f, 0.f};
            sacc[mi][0] = __builtin_amdgcn_mfma_f32_16x16x32_bf16(
                a1, qf[0][1],
                __builtin_amdgcn_mfma_f32_16x16x32_bf16(a0, qf[0][0], z, 0, 0, 0), 0, 0, 0);
            sacc[mi][1] = __builtin_amdgcn_mfma_f32_16x16x32_bf16(
                a1, qf[1][1],
                __builtin_amdgcn_mfma_f32_16x16x32_bf16(a0, qf[1][0], z, 0, 0, 0), 0, 0, 0);
        }

#pragma unroll
        for (int s = 0; s < 2; s++) {
            // online softmax (exp2 domain); stats per q-column (lr)
            float mloc = -1e30f;
#pragma unroll
            for (int mi = 0; mi < 8; mi++)
#pragma unroll
                for (int r = 0; r < 4; r++) mloc = fmaxf(mloc, sacc[mi][s][r]);
            mloc = fmaxf(mloc, __shfl_xor(mloc, 16, 64));
            mloc = fmaxf(mloc, __shfl_xor(mloc, 32, 64));
            const float m_new = fmaxf(m_run[s], mloc);
            const float alpha = __builtin_amdgcn_exp2f(m_run[s] - m_new);
            m_run[s] = m_new;

            float psum = 0.f;
#pragma unroll
            for (int mi = 0; mi < 8; mi++)
#pragma unroll
                for (int r = 0; r < 4; r++) {
                    const float p = __builtin_amdgcn_exp2f(sacc[mi][s][r] - m_new);
                    sacc[mi][s][r] = p;
                    psum += p;
                }
            psum += __shfl_xor(psum, 16, 64);
            psum += __shfl_xor(psum, 32, 64);
            l_run[s] = l_run[s] * alpha + psum;

            float ar[4];
#pragma unroll
            for (int r = 0; r < 4; r++) ar[r] = __shfl(alpha, quad * 4 + r, 64);
#pragma unroll
            for (int nj = 0; nj < 4; nj++)
#pragma unroll
                for (int r = 0; r < 4; r++) oacc[s][nj][r] *= ar[r];

            // pack P rows (wave-private; same-wave ds ordering, no barrier)
            const int prow = s * 64 + wave * 16 + lr;
#pragma unroll
            for (int mi = 0; mi < 8; mi++) {
                uint2 w;
                w.x = pk2(sacc[mi][s][0], sacc[mi][s][1]);
                w.y = pk2(sacc[mi][s][2], sacc[mi][s][3]);
                *(uint2*)&sP[prow * 80 + mi * 16 + quad * 4] = w;
            }
            // PV: O[q][dk] += P[q][key] · Vt[dk][key]
#pragma unroll
            for (int kk = 0; kk < 4; kk++) {
                const bf16x8 pa = *(const bf16x8*)&sP[prow * 80 + kk * 32 + quad * 8];
#pragma unroll
                for (int nj = 0; nj < 4; nj++) {
                    const bf16x8 bb = *(const bf16x8*)&bvr[nj * 4 + kk];
                    oacc[s][nj] = __builtin_amdgcn_mfma_f32_16x16x32_bf16(
                        pa, bb, oacc[s][nj], 0, 0, 0);
                }
            }
        }
    }

    // epilogue
    const int b = bh >> 4, h = bh & (NH - 1);
#pragma unroll
    for (int s = 0; s < 2; s++) {
        const float inv = 1.0f / l_run[s];
        float ivr[4];
#pragma unroll
        for (int r = 0; r < 4; r++) ivr[r] = __shfl(inv, quad * 4 + r, 64);
#pragma unroll
        for (int nj = 0; nj < 4; nj++)
#pragma unroll
            for (int r = 0; r < 4; r++) {
                const int qg = q0 + s * 64 + wave * 16 + quad * 4 + r;
                const long oi = ((long)(b * S_LEN + qg)) * DM + h * DK + nj * 16 + lr;
                Out[oi] = rne16(oacc[s][nj][r] * ivr[r]);
            }
    }
}

// ---------------------------------------------------------------------------
// Residual + LayerNorm: out = LN(X + O) * gamma + beta. X fp32, O bf16.
// ---------------------------------------------------------------------------
__global__ __launch_bounds__(256) void ln_res(
    const float* __restrict__ X,
    const u16* __restrict__ O,
    const float* __restrict__ gamma,
    const float* __restrict__ beta,
    float* __restrict__ Out)
{
    __shared__ float sR[8];
    const int row = blockIdx.x;
    const int t = threadIdx.x;
    const int lane = t & 63, wave = t >> 6;
    const long off = (long)row * DM + t * 4;

    const float4 x4 = *(const float4*)(X + off);
    const uint2  uo = *(const uint2*)(O + off);
    float x[4];
    x[0] = x4.x + bf2f((u16)(uo.x & 0xffffu));
    x[1] = x4.y + bf2f((u16)(uo.x >> 16));
    x[2] = x4.z + bf2f((u16)(uo.y & 0xffffu));
    x[3] = x4.w + bf2f((u16)(uo.y >> 16));

    float s  = x[0] + x[1] + x[2] + x[3];
    float ss = x[0] * x[0] + x[1] * x[1] + x[2] * x[2] + x[3] * x[3];
#pragma unroll
    for (int o2 = 32; o2 > 0; o2 >>= 1) {
        s  += __shfl_xor(s, o2, 64);
        ss += __shfl_xor(ss, o2, 64);
    }
    if (lane == 0) { sR[wave] = s; sR[4 + wave] = ss; }
    __syncthreads();
    if (t == 0) {
        sR[0] = sR[0] + sR[1] + sR[2] + sR[3];
        sR[4] = sR[4] + sR[5] + sR[6] + sR[7];
    }
    __syncthreads();
    const float mean = sR[0] * (1.0f / DM);
    const float var  = sR[4] * (1.0f / DM) - mean * mean;
    const float rstd = rsqrtf(var + 1e-5f);

    const float4 g4 = *(const float4*)(gamma + t * 4);
    const float4 b4 = *(const float4*)(beta + t * 4);
    float4 r;
    r.x = (x[0] - mean) * rstd * g4.x + b4.x;
    r.y = (x[1] - mean) * rstd * g4.y + b4.y;
    r.z = (x[2] - mean) * rstd * g4.z + b4.z;
    r.w = (x[3] - mean) * rstd * g4.w + b4.w;
    *(float4*)(Out + off) = r;
}

// ---------------------------------------------------------------------------
// ws (32 MB): [0,8) Q16 -> Ob | [8,16) K16 -> Vtb | [16,18) Wq16 | [18,20)
// Wk16 | [20,22) Wv16 | [22,24) Wo16 | [24,32) Kb.
// d_out (16 MB): [0,8) V16 -> Ab | [8,16) Qb; ln_res overwrites all at end.
// Timeline: cvt -> gemmQK(z=2) -> gemmV -> attn -> gemmWo -> ln. Each region
// is dead before its reuse (verified above).
// ---------------------------------------------------------------------------
extern "C" void kernel_launch(void* const* d_in, const int* in_sizes, int n_in,
                              void* d_out, int out_size, void* d_ws, size_t ws_size,
                              hipStream_t stream)
{
    (void)in_sizes; (void)n_in; (void)out_size; (void)ws_size;
    const float* queries = (const float*)d_in[0];
    const float* keys    = (const float*)d_in[1];
    const float* values  = (const float*)d_in[2];
    const float* Wq = (const float*)d_in[3];
    const float* bq = (const float*)d_in[4];
    const float* Wk = (const float*)d_in[5];
    const float* bk = (const float*)d_in[6];
    const float* Wv = (const float*)d_in[7];
    const float* bv = (const float*)d_in[8];
    const float* Wo = (const float*)d_in[9];
    const float* bo = (const float*)d_in[10];
    const float* gamma = (const float*)d_in[11];
    const float* beta  = (const float*)d_in[12];

    char* ws = (char*)d_ws;
    const size_t MB = (size_t)1024 * 1024;
    u16* Q16  = (u16*)(ws);
    u16* K16  = (u16*)(ws + 8 * MB);
    u16* Wq16 = (u16*)(ws + 16 * MB);
    u16* Wk16 = (u16*)(ws + 18 * MB);
    u16* Wv16 = (u16*)(ws + 20 * MB);
    u16* Wo16 = (u16*)(ws + 22 * MB);
    u16* Kb   = (u16*)(ws + 24 * MB);
    u16* Ob   = Q16;                              // over Q16 (dead)
    u16* Vtb  = K16;                              // over K16 (dead)
    u16* V16  = (u16*)d_out;                      // d_out[0,8)
    u16* Qb   = (u16*)((char*)d_out + 8 * MB);    // d_out[8,16)
    u16* Ab   = (u16*)d_out;                      // over V16 (dead)

    const float CS = 0.18033688011112042f;  // log2(e)/sqrt(64)

    cvt_all<<<8192, 256, 0, stream>>>(queries, keys, values, Wq, Wk, Wv, Wo,
                                      Q16, K16, V16, Wq16, Wk16, Wv16, Wo16);
    gemm64<<<dim3(16, 32, 2), 256, 0, stream>>>(
        Q16, Wq16, bq, Qb, CS, 1,
        K16, Wk16, bk, Kb, 1.0f, 1);
    gemm64<<<dim3(16, 32, 1), 256, 0, stream>>>(
        V16, Wv16, bv, Vtb, 1.0f, 2,
        V16, Wv16, bv, Vtb, 1.0f, 2);
    attn_flash<<<dim3(S_LEN / 128, BATCH * NH), 256, 0, stream>>>(Qb, Kb, Vtb, Ab);
    gemm64<<<dim3(16, 32, 1), 256, 0, stream>>>(
        Ab, Wo16, bo, Ob, 1.0f, 3,
        Ab, Wo16, bo, Ob, 1.0f, 3);
    ln_res<<<M_ROWS, 256, 0, stream>>>(queries, Ob, gamma, beta, (float*)d_out);
}

// Round 8
// 258.189 us; speedup vs baseline: 14.2843x; 1.0752x over previous
//
#include <hip/hip_runtime.h>

#define S_LEN 2048
#define BATCH 2
#define DM 1024
#define NH 16
#define DK 64
#define M_ROWS 4096

typedef __bf16 bf16x8 __attribute__((ext_vector_type(8)));
typedef float f32x4 __attribute__((ext_vector_type(4)));
typedef unsigned int u32;
typedef unsigned short u16;

__device__ __forceinline__ float bf2f(u16 u) {
    union { u32 i; float f; } v;
    v.i = ((u32)u) << 16;
    return v.f;
}

// round-to-nearest-even fp32 -> bf16 (finite)
__device__ __forceinline__ u16 rne16(float f) {
    u32 i = __builtin_bit_cast(u32, f);
    return (u16)((i + 0x7fffu + ((i >> 16) & 1u)) >> 16);
}

// pack two fp32 -> bf16x2 (round-half-up; finite)
__device__ __forceinline__ u32 pk2(float x, float y) {
    u32 a = __builtin_bit_cast(u32, x) + 0x8000u;
    u32 b = __builtin_bit_cast(u32, y) + 0x8000u;
    return (a >> 16) | (b & 0xffff0000u);
}

// async global->LDS, 16B per lane
__device__ __forceinline__ void async16(const void* g, void* l) {
    __builtin_amdgcn_global_load_lds(
        (const __attribute__((address_space(1))) u32*)((unsigned long long)g),
        (__attribute__((address_space(3))) u32*)((u32)(unsigned long long)l),
        16, 0, 0);
}

// ---------------------------------------------------------------------------
// One-shot fp32->bf16 of all 7 tensors (2048 elems / block).
// ---------------------------------------------------------------------------
__global__ __launch_bounds__(256) void cvt_all(
    const float* __restrict__ q, const float* __restrict__ k,
    const float* __restrict__ v, const float* __restrict__ wq,
    const float* __restrict__ wk, const float* __restrict__ wv,
    const float* __restrict__ wo,
    u16* q16, u16* k16, u16* v16, u16* wq16, u16* wk16, u16* wv16, u16* wo16)
{
    const int b = blockIdx.x;
    const float* src; u16* dst; long off;
    if (b < 2048)      { src = q;  dst = q16;  off = (long)b * 2048; }
    else if (b < 4096) { src = k;  dst = k16;  off = (long)(b - 2048) * 2048; }
    else if (b < 6144) { src = v;  dst = v16;  off = (long)(b - 4096) * 2048; }
    else if (b < 6656) { src = wq; dst = wq16; off = (long)(b - 6144) * 2048; }
    else if (b < 7168) { src = wk; dst = wk16; off = (long)(b - 6656) * 2048; }
    else if (b < 7680) { src = wv; dst = wv16; off = (long)(b - 7168) * 2048; }
    else               { src = wo; dst = wo16; off = (long)(b - 7680) * 2048; }
    const long i = off + (long)threadIdx.x * 8;
    const float4 a = *(const float4*)(src + i);
    const float4 c = *(const float4*)(src + i + 4);
    uint4 r;
    r.x = pk2(a.x, a.y); r.y = pk2(a.z, a.w);
    r.z = pk2(c.x, c.y); r.w = pk2(c.z, c.w);
    *(uint4*)(dst + i) = r;
}

// ---------------------------------------------------------------------------
// bf16 GEMM, BMx128 tile (BM=128 or 64), BK=32, K=N=1024.
// Double-buffered global_load_lds staging (single barrier/iter), XOR-swizzled
// chunk placement (chunk (row,c) -> slot row*4 + (c^(row&3))).
// Epilogue: accumulators -> bf16 LDS tile -> coalesced uint4 global writes.
// mode 1: [B,H,S,DK] (Q/K); mode 2: [B,H,DK,S] (V^T); mode 3: [M,1024].
// blockIdx.z selects one of three arg sets (fused QKV launch).
// NOTE: no LDS pointer arrays (addrspacecast static-init is rejected on
// gfx950) — buffer selection is done with offset arithmetic.
// ---------------------------------------------------------------------------
template <int BM>
__global__ __launch_bounds__(256) void gemm_t(
    const u16* __restrict__ A0, const u16* __restrict__ W0,
    const float* __restrict__ bi0, u16* __restrict__ C0, float s0, int md0,
    const u16* __restrict__ A1, const u16* __restrict__ W1,
    const float* __restrict__ bi1, u16* __restrict__ C1, float s1, int md1,
    const u16* __restrict__ A2, const u16* __restrict__ W2,
    const float* __restrict__ bi2, u16* __restrict__ C2, float s2, int md2)
{
    constexpr int IT = BM / 32;        // i-tiles per wave
    constexpr int ASZ = BM * 32;       // one A buffer
    constexpr int BSZ = 128 * 32;      // one B buffer
    __shared__ u16 smem[2 * ASZ + 2 * BSZ];

    const int z = blockIdx.z;
    const u16* A = z == 0 ? A0 : (z == 1 ? A1 : A2);
    const u16* W = z == 0 ? W0 : (z == 1 ? W1 : W2);
    const float* bias = z == 0 ? bi0 : (z == 1 ? bi1 : bi2);
    u16* C = z == 0 ? C0 : (z == 1 ? C1 : C2);
    const float scale = z == 0 ? s0 : (z == 1 ? s1 : s2);
    const int mode = z == 0 ? md0 : (z == 1 ? md1 : md2);

    const int t    = threadIdx.x;
    const int lane = t & 63;
    const int wave = t >> 6;
    const int quad = lane >> 4;
    const int lr   = lane & 15;
    const int wm   = (wave >> 1) * (BM / 2);
    const int wn   = (wave & 1) * 64;
    const int m0   = blockIdx.y * BM;
    const int n0   = blockIdx.x * 128;

    f32x4 acc[IT][4];
#pragma unroll
    for (int i = 0; i < IT; i++)
#pragma unroll
        for (int j = 0; j < 4; j++) acc[i][j] = (f32x4){0.f, 0.f, 0.f, 0.f};

    // DMA sources (swizzled placement, as validated in round 6)
    const u16 *gA0, *gA1 = nullptr, *gW0, *gW1;
    {
        int c = t, r = c >> 2, cc = (c & 3) ^ (r & 3);
        gA0 = A + (long)(m0 + r) * 1024 + cc * 8;
        if (BM == 128) {
            c = t + 256; r = c >> 2; cc = (c & 3) ^ (r & 3);
            gA1 = A + (long)(m0 + r) * 1024 + cc * 8;
        }
        c = t; r = c >> 2; cc = (c & 3) ^ (r & 3);
        gW0 = W + (long)(n0 + r) * 1024 + cc * 8;
        c = t + 256; r = c >> 2; cc = (c & 3) ^ (r & 3);
        gW1 = W + (long)(n0 + r) * 1024 + cc * 8;
    }

    // prologue DMA into buf 0
    async16(gA0, smem + t * 8);
    if constexpr (BM == 128) async16(gA1, smem + (t + 256) * 8);
    async16(gW0, smem + 2 * ASZ + t * 8);
    async16(gW1, smem + 2 * ASZ + (t + 256) * 8);

    const int sw = quad ^ (lr & 3);

    for (int kb = 0; kb < 32; kb++) {
        __syncthreads();  // drains DMA for buf kb&1; all waves done with other
        if (kb < 31) {
            const int k1 = (kb + 1) * 32;
            u16* dA = smem + ((kb + 1) & 1) * ASZ;
            u16* dB = smem + 2 * ASZ + ((kb + 1) & 1) * BSZ;
            async16(gA0 + k1, dA + t * 8);
            if constexpr (BM == 128) async16(gA1 + k1, dA + (t + 256) * 8);
            async16(gW0 + k1, dB + t * 8);
            async16(gW1 + k1, dB + (t + 256) * 8);
        }
        const u16* sa = smem + (kb & 1) * ASZ;
        const u16* sb = smem + 2 * ASZ + (kb & 1) * BSZ;
        bf16x8 aF[IT], bF[4];
#pragma unroll
        for (int i = 0; i < IT; i++)
            aF[i] = *(const bf16x8*)&sa[((wm + i * 16 + lr) * 4 + sw) * 8];
#pragma unroll
        for (int j = 0; j < 4; j++)
            bF[j] = *(const bf16x8*)&sb[((wn + j * 16 + lr) * 4 + sw) * 8];
#pragma unroll
        for (int i = 0; i < IT; i++)
#pragma unroll
            for (int j = 0; j < 4; j++)
                acc[i][j] = __builtin_amdgcn_mfma_f32_16x16x32_bf16(
                    aF[i], bF[j], acc[i][j], 0, 0, 0);
    }

    // ---- coalesced epilogue via LDS (C/D layout: col=lr, row=quad*4+r) ----
    u16* sO = smem;
    const int b_ = m0 >> 11;  // batch index (tile never straddles)

    if constexpr (BM == 64) {
        // mode 3 only: [M,1024] rows. sO [64][136]
        __syncthreads();
#pragma unroll
        for (int i = 0; i < IT; i++)
#pragma unroll
            for (int j = 0; j < 4; j++) {
                const float bvv = bias[n0 + wn + j * 16 + lr];
#pragma unroll
                for (int r = 0; r < 4; r++) {
                    const int gmL = wm + i * 16 + quad * 4 + r;
                    sO[gmL * 136 + wn + j * 16 + lr] =
                        rne16((acc[i][j][r] + bvv) * scale);
                }
            }
        __syncthreads();
#pragma unroll
        for (int i = 0; i < 4; i++) {
            const int c = t + i * 256;
            const int row = c >> 4, c8 = c & 15;
            *(uint4*)(C + (long)(m0 + row) * 1024 + n0 + c8 * 8) =
                *(const uint4*)&sO[row * 136 + c8 * 8];
        }
    } else if (mode == 1) {
        // [B,H,S,DK]; two passes over gm halves. sO [64][136]
#pragma unroll
        for (int pass = 0; pass < 2; pass++) {
            __syncthreads();
            if ((wave >> 1) == pass) {
#pragma unroll
                for (int i = 0; i < IT; i++)
#pragma unroll
                    for (int j = 0; j < 4; j++) {
                        const float bvv = bias[n0 + wn + j * 16 + lr];
#pragma unroll
                        for (int r = 0; r < 4; r++) {
                            const int gmL = i * 16 + quad * 4 + r;  // 0..63
                            sO[gmL * 136 + wn + j * 16 + lr] =
                                rne16((acc[i][j][r] + bvv) * scale);
                        }
                    }
            }
            __syncthreads();
#pragma unroll
            for (int i = 0; i < 4; i++) {
                const int c = t + i * 256;
                const int row = c >> 4, c8 = c & 15;
                const int gm = m0 + pass * 64 + row;
                const int gn = n0 + c8 * 8;
                const long idx = (((long)b_ * NH + (gn >> 6)) * S_LEN
                                  + (gm & (S_LEN - 1))) * DK + (gn & 63);
                *(uint4*)(C + idx) = *(const uint4*)&sO[row * 136 + c8 * 8];
            }
        }
    } else {
        // mode 2: [B,H,DK,S]; two passes over gm halves. sO [128 gn][72]
#pragma unroll
        for (int pass = 0; pass < 2; pass++) {
            __syncthreads();
            if ((wave >> 1) == pass) {
#pragma unroll
                for (int i = 0; i < IT; i++)
#pragma unroll
                    for (int j = 0; j < 4; j++) {
                        const float bvv = bias[n0 + wn + j * 16 + lr];
                        const u16 v0 = rne16((acc[i][j][0] + bvv) * scale);
                        const u16 v1 = rne16((acc[i][j][1] + bvv) * scale);
                        const u16 v2 = rne16((acc[i][j][2] + bvv) * scale);
                        const u16 v3 = rne16((acc[i][j][3] + bvv) * scale);
                        uint2 w;
                        w.x = (u32)v0 | ((u32)v1 << 16);
                        w.y = (u32)v2 | ((u32)v3 << 16);
                        *(uint2*)&sO[(wn + j * 16 + lr) * 72 + i * 16 + quad * 4] = w;
                    }
            }
            __syncthreads();
#pragma unroll
            for (int i = 0; i < 4; i++) {
                const int c = t + i * 256;
                const int row = c >> 3, c8 = c & 7;  // row = gnL 0..127
                const int gn = n0 + row;
                const int s = m0 + pass * 64 + c8 * 8;
                const long idx = (((long)b_ * NH + (gn >> 6)) * DK
                                  + (gn & 63)) * S_LEN + (s & (S_LEN - 1));
                *(uint4*)(C + idx) = *(const uint4*)&sO[row * 72 + c8 * 8];
            }
        }
    }
}

// ---------------------------------------------------------------------------
// Flash attention (unchanged from round 6). Block = 128 q of one (b,h).
// K DMA double-buffered, XOR-swizzled; V frags direct from global V^T;
// Q pre-scaled by log2(e)/sqrt(dk); online softmax in exp2 domain.
// ---------------------------------------------------------------------------
__global__ __launch_bounds__(256, 2) void attn_flash(
    const u16* __restrict__ Q,
    const u16* __restrict__ K,
    const u16* __restrict__ Vt,
    u16* __restrict__ Out)
{
    __shared__ u16 sK[2][8192];
    __shared__ u16 sP[128 * 80];

    const int t    = threadIdx.x;
    const int lane = t & 63;
    const int wave = t >> 6;
    const int quad = lane >> 4;
    const int lr   = lane & 15;
    const int q0   = blockIdx.x * 128;
    const int bh   = blockIdx.y;

    const long baseQK = (long)bh * S_LEN * DK;
    const long baseV  = (long)bh * DK * S_LEN;

#pragma unroll
    for (int i = 0; i < 4; i++) {
        const int l = t + i * 256;
        const int row = l >> 3, c8 = l & 7;
        *(uint4*)&sP[row * 72 + c8 * 8] =
            *(const uint4*)(Q + baseQK + (long)(q0 + row) * DK + c8 * 8);
    }

    const u16* gK[4];
#pragma unroll
    for (int i = 0; i < 4; i++) {
        const int l = t + i * 256;
        const int h = l >> 9, rem = l & 511;
        const int row = rem >> 2, c = (rem & 3) ^ (row & 3);
        gK[i] = K + baseQK + row * DK + h * 32 + c * 8;
    }
#pragma unroll
    for (int i = 0; i < 4; i++)
        async16(gK[i], &sK[0][(t + i * 256) * 8]);
    __syncthreads();

    bf16x8 qf[2][2];
#pragma unroll
    for (int s = 0; s < 2; s++)
#pragma unroll
        for (int h = 0; h < 2; h++)
            qf[s][h] = *(const bf16x8*)&sP[(s * 64 + wave * 16 + lr) * 72 + h * 32 + quad * 8];

    f32x4 oacc[2][4];
#pragma unroll
    for (int s = 0; s < 2; s++)
#pragma unroll
        for (int nj = 0; nj < 4; nj++) oacc[s][nj] = (f32x4){0.f, 0.f, 0.f, 0.f};
    float m_run[2] = {-1e30f, -1e30f}, l_run[2] = {0.f, 0.f};

    const int sw = quad ^ (lr & 3);

    for (int kb = 0; kb < S_LEN / 128; kb++) {
        const int buf = kb & 1, nb = buf ^ 1;
        __syncthreads();

        uint4 bvr[16];
#pragma unroll
        for (int nj = 0; nj < 4; nj++)
#pragma unroll
            for (int kk = 0; kk < 4; kk++)
                bvr[nj * 4 + kk] = *(const uint4*)(Vt + baseV
                    + (long)(nj * 16 + lr) * S_LEN + kb * 128 + kk * 32 + quad * 8);

        if (kb + 1 < S_LEN / 128) {
#pragma unroll
            for (int i = 0; i < 4; i++)
                async16(gK[i] + (long)(kb + 1) * 128 * DK, &sK[nb][(t + i * 256) * 8]);
        }

        f32x4 sacc[8][2];
#pragma unroll
        for (int mi = 0; mi < 8; mi++) {
            const bf16x8 a0 = *(const bf16x8*)&sK[buf][(((mi * 16 + lr) * 4) + sw) * 8];
            const bf16x8 a1 = *(const bf16x8*)&sK[buf][((512 + (mi * 16 + lr) * 4) + sw) * 8];
            const f32x4 z = (f32x4){0.f, 0.f, 0.f, 0.f};
            sacc[mi][0] = __builtin_amdgcn_mfma_f32_16x16x32_bf16(
                a1, qf[0][1],
                __builtin_amdgcn_mfma_f32_16x16x32_bf16(a0, qf[0][0], z, 0, 0, 0), 0, 0, 0);
            sacc[mi][1] = __builtin_amdgcn_mfma_f32_16x16x32_bf16(
                a1, qf[1][1],
                __builtin_amdgcn_mfma_f32_16x16x32_bf16(a0, qf[1][0], z, 0, 0, 0), 0, 0, 0);
        }

#pragma unroll
        for (int s = 0; s < 2; s++) {
            float mloc = -1e30f;
#pragma unroll
            for (int mi = 0; mi < 8; mi++)
#pragma unroll
                for (int r = 0; r < 4; r++) mloc = fmaxf(mloc, sacc[mi][s][r]);
            mloc = fmaxf(mloc, __shfl_xor(mloc, 16, 64));
            mloc = fmaxf(mloc, __shfl_xor(mloc, 32, 64));
            const float m_new = fmaxf(m_run[s], mloc);
            const float alpha = __builtin_amdgcn_exp2f(m_run[s] - m_new);
            m_run[s] = m_new;

            float psum = 0.f;
#pragma unroll
            for (int mi = 0; mi < 8; mi++)
#pragma unroll
                for (int r = 0; r < 4; r++) {
                    const float p = __builtin_amdgcn_exp2f(sacc[mi][s][r] - m_new);
                    sacc[mi][s][r] = p;
                    psum += p;
                }
            psum += __shfl_xor(psum, 16, 64);
            psum += __shfl_xor(psum, 32, 64);
            l_run[s] = l_run[s] * alpha + psum;

            float ar[4];
#pragma unroll
            for (int r = 0; r < 4; r++) ar[r] = __shfl(alpha, quad * 4 + r, 64);
#pragma unroll
            for (int nj = 0; nj < 4; nj++)
#pragma unroll
                for (int r = 0; r < 4; r++) oacc[s][nj][r] *= ar[r];

            const int prow = s * 64 + wave * 16 + lr;
#pragma unroll
            for (int mi = 0; mi < 8; mi++) {
                uint2 w;
                w.x = pk2(sacc[mi][s][0], sacc[mi][s][1]);
                w.y = pk2(sacc[mi][s][2], sacc[mi][s][3]);
                *(uint2*)&sP[prow * 80 + mi * 16 + quad * 4] = w;
            }
#pragma unroll
            for (int kk = 0; kk < 4; kk++) {
                const bf16x8 pa = *(const bf16x8*)&sP[prow * 80 + kk * 32 + quad * 8];
#pragma unroll
                for (int nj = 0; nj < 4; nj++) {
                    const bf16x8 bb = *(const bf16x8*)&bvr[nj * 4 + kk];
                    oacc[s][nj] = __builtin_amdgcn_mfma_f32_16x16x32_bf16(
                        pa, bb, oacc[s][nj], 0, 0, 0);
                }
            }
        }
    }

    const int b = bh >> 4, h = bh & (NH - 1);
#pragma unroll
    for (int s = 0; s < 2; s++) {
        const float inv = 1.0f / l_run[s];
        float ivr[4];
#pragma unroll
        for (int r = 0; r < 4; r++) ivr[r] = __shfl(inv, quad * 4 + r, 64);
#pragma unroll
        for (int nj = 0; nj < 4; nj++)
#pragma unroll
            for (int r = 0; r < 4; r++) {
                const int qg = q0 + s * 64 + wave * 16 + quad * 4 + r;
                const long oi = ((long)(b * S_LEN + qg)) * DM + h * DK + nj * 16 + lr;
                Out[oi] = rne16(oacc[s][nj][r] * ivr[r]);
            }
    }
}

// ---------------------------------------------------------------------------
// Residual + LayerNorm: out = LN(X + O) * gamma + beta. X fp32, O bf16.
// ---------------------------------------------------------------------------
__global__ __launch_bounds__(256) void ln_res(
    const float* __restrict__ X,
    const u16* __restrict__ O,
    const float* __restrict__ gamma,
    const float* __restrict__ beta,
    float* __restrict__ Out)
{
    __shared__ float sR[8];
    const int row = blockIdx.x;
    const int t = threadIdx.x;
    const int lane = t & 63, wave = t >> 6;
    const long off = (long)row * DM + t * 4;

    const float4 x4 = *(const float4*)(X + off);
    const uint2  uo = *(const uint2*)(O + off);
    float x[4];
    x[0] = x4.x + bf2f((u16)(uo.x & 0xffffu));
    x[1] = x4.y + bf2f((u16)(uo.x >> 16));
    x[2] = x4.z + bf2f((u16)(uo.y & 0xffffu));
    x[3] = x4.w + bf2f((u16)(uo.y >> 16));

    float s  = x[0] + x[1] + x[2] + x[3];
    float ss = x[0] * x[0] + x[1] * x[1] + x[2] * x[2] + x[3] * x[3];
#pragma unroll
    for (int o2 = 32; o2 > 0; o2 >>= 1) {
        s  += __shfl_xor(s, o2, 64);
        ss += __shfl_xor(ss, o2, 64);
    }
    if (lane == 0) { sR[wave] = s; sR[4 + wave] = ss; }
    __syncthreads();
    if (t == 0) {
        sR[0] = sR[0] + sR[1] + sR[2] + sR[3];
        sR[4] = sR[4] + sR[5] + sR[6] + sR[7];
    }
    __syncthreads();
    const float mean = sR[0] * (1.0f / DM);
    const float var  = sR[4] * (1.0f / DM) - mean * mean;
    const float rstd = rsqrtf(var + 1e-5f);

    const float4 g4 = *(const float4*)(gamma + t * 4);
    const float4 b4 = *(const float4*)(beta + t * 4);
    float4 r;
    r.x = (x[0] - mean) * rstd * g4.x + b4.x;
    r.y = (x[1] - mean) * rstd * g4.y + b4.y;
    r.z = (x[2] - mean) * rstd * g4.z + b4.z;
    r.w = (x[3] - mean) * rstd * g4.w + b4.w;
    *(float4*)(Out + off) = r;
}

// ---------------------------------------------------------------------------
// ws (32 MB): [0,8) Q16 -> Ob | [8,16) K16 -> Vtb | [16,18) Wq16 | [18,20)
// Wk16 | [20,22) Wv16 | [22,24) Wo16 | [24,32) Kb.
// d_out (16 MB): [0,8) V16 -> Ab | [8,16) Qb; ln_res overwrites all at end.
// Timeline: cvt -> gemmQKV(z=3) -> attn -> gemmWo -> ln.
// ---------------------------------------------------------------------------
extern "C" void kernel_launch(void* const* d_in, const int* in_sizes, int n_in,
                              void* d_out, int out_size, void* d_ws, size_t ws_size,
                              hipStream_t stream)
{
    (void)in_sizes; (void)n_in; (void)out_size; (void)ws_size;
    const float* queries = (const float*)d_in[0];
    const float* keys    = (const float*)d_in[1];
    const float* values  = (const float*)d_in[2];
    const float* Wq = (const float*)d_in[3];
    const float* bq = (const float*)d_in[4];
    const float* Wk = (const float*)d_in[5];
    const float* bk = (const float*)d_in[6];
    const float* Wv = (const float*)d_in[7];
    const float* bv = (const float*)d_in[8];
    const float* Wo = (const float*)d_in[9];
    const float* bo = (const float*)d_in[10];
    const float* gamma = (const float*)d_in[11];
    const float* beta  = (const float*)d_in[12];

    char* ws = (char*)d_ws;
    const size_t MB = (size_t)1024 * 1024;
    u16* Q16  = (u16*)(ws);
    u16* K16  = (u16*)(ws + 8 * MB);
    u16* Wq16 = (u16*)(ws + 16 * MB);
    u16* Wk16 = (u16*)(ws + 18 * MB);
    u16* Wv16 = (u16*)(ws + 20 * MB);
    u16* Wo16 = (u16*)(ws + 22 * MB);
    u16* Kb   = (u16*)(ws + 24 * MB);
    u16* Ob   = Q16;                              // over Q16 (dead)
    u16* Vtb  = K16;                              // over K16 (dead)
    u16* V16  = (u16*)d_out;                      // d_out[0,8)
    u16* Qb   = (u16*)((char*)d_out + 8 * MB);    // d_out[8,16)
    u16* Ab   = (u16*)d_out;                      // over V16 (dead)

    const float CS = 0.18033688011112042f;  // log2(e)/sqrt(64)

    cvt_all<<<8192, 256, 0, stream>>>(queries, keys, values, Wq, Wk, Wv, Wo,
                                      Q16, K16, V16, Wq16, Wk16, Wv16, Wo16);
    gemm_t<128><<<dim3(8, 32, 3), 256, 0, stream>>>(
        Q16, Wq16, bq, Qb, CS, 1,
        K16, Wk16, bk, Kb, 1.0f, 1,
        V16, Wv16, bv, Vtb, 1.0f, 2);
    attn_flash<<<dim3(S_LEN / 128, BATCH * NH), 256, 0, stream>>>(Qb, Kb, Vtb, Ab);
    gemm_t<64><<<dim3(8, 64, 1), 256, 0, stream>>>(
        Ab, Wo16, bo, Ob, 1.0f, 3,
        Ab, Wo16, bo, Ob, 1.0f, 3,
        Ab, Wo16, bo, Ob, 1.0f, 3);
    ln_res<<<M_ROWS, 256, 0, stream>>>(queries, Ob, gamma, beta, (float*)d_out);
}